// Round 8
// baseline (812.682 us; speedup 1.0000x reference)
//
#include <hip/hip_runtime.h>
#include <stdint.h>

typedef uint32_t u32;
typedef uint64_t u64;
typedef uint16_t u16;

#define NCLS 81
#define TOPK 200
#define KEEPK 200
#define CONF_THR 0.01f
#define NMS_THR 0.45f
#define NB 32
#define NP 24564
#define NPPAD 24576            /* row padded to 16B multiple */
#define NP2 (NP / 2)           /* 12282 */
#define NP2PAD (NPPAD / 2)     /* 12288 u32 words */
#define DW4 (NP2PAD / 4)       /* 3072 uint4 per row */
#define NFLAT (NCLS * TOPK)    /* 16200 */
#define NPCHUNK 256
#define NCHUNK ((NP + NPCHUNK - 1) / NPCHUNK) /* 96 */

// order-preserving map float -> u32 (ascending)
__device__ __forceinline__ u32 fkey(float f) {
  u32 u = __float_as_uint(f);
  return (u & 0x80000000u) ? ~u : (u | 0x80000000u);
}
__device__ __forceinline__ float unfkey(u32 k) {
  u32 u = (k & 0x80000000u) ? (k & 0x7FFFFFFFu) : ~k;
  return __uint_as_float(u);
}

// fkey(-1.0f) = 0x407FFFFF; top 16 bits = 0x407F
#define NEGKEY 0x407FFFFFu
#define NEGK16 0x407Fu

// ---------------------------------------------------------------------------
// Kernel 0: coalesced conf read -> thresholded u16 keys, transposed [B][C][NPPAD]
// ---------------------------------------------------------------------------
__global__ __launch_bounds__(256) void build_keys(const float* __restrict__ conf,
                                                  u16* __restrict__ keys16) {
  __shared__ u16 tile[NCLS][NPCHUNK + 2];  // 81 x 258 u16

  const int tid = threadIdx.x;
  const int blk = blockIdx.x;
  const int b = blk / NCHUNK, chunk = blk % NCHUNK;
  const int p0 = chunk * NPCHUNK;
  const int cnt = min(NPCHUNK, NP - p0);  // 256 or 244 (even)
  const int tot = cnt * NCLS;
  const float* src = conf + ((size_t)b * NP + p0) * NCLS;  // 16B-aligned

  for (int f4 = tid * 4; f4 < tot; f4 += 256 * 4) {
    if (f4 + 3 < tot) {
      float4 v = *reinterpret_cast<const float4*>(src + f4);
      float vv[4] = {v.x, v.y, v.z, v.w};
#pragma unroll
      for (int j = 0; j < 4; ++j) {
        int f = f4 + j;
        int pi = f / NCLS, c = f - pi * NCLS;
        float s = vv[j];
        s = (s > CONF_THR) ? s : -1.0f;
        tile[c][pi] = (u16)(fkey(s) >> 16);
      }
    } else {
      for (int f = f4; f < tot; ++f) {
        int pi = f / NCLS, c = f - pi * NCLS;
        float s = src[f];
        s = (s > CONF_THR) ? s : -1.0f;
        tile[c][pi] = (u16)(fkey(s) >> 16);
      }
    }
  }
  __syncthreads();

  const int halves = cnt >> 1;  // 128 or 122
  u32* dst32 = (u32*)keys16;
  if (halves == 128) {
    for (int i = tid; i < NCLS * 128; i += 256) {
      int c = i >> 7, w = i & 127;
      u32 lo = tile[c][2 * w], hi = tile[c][2 * w + 1];
      size_t rowbase = ((size_t)b * NCLS + c) * NP2PAD + (p0 >> 1);
      dst32[rowbase + w] = lo | (hi << 16);
    }
  } else {
    for (int i = tid; i < NCLS * halves; i += 256) {
      int c = i / halves, w = i - c * halves;
      u32 lo = tile[c][2 * w], hi = tile[c][2 * w + 1];
      size_t rowbase = ((size_t)b * NCLS + c) * NP2PAD + (p0 >> 1);
      dst32[rowbase + w] = lo | (hi << 16);
    }
    // last chunk: zero the 6 pad words per class (keys sort below everything)
    for (int i = tid; i < NCLS * 6; i += 256) {
      int c = i / 6, w = i - c * 6;
      dst32[((size_t)b * NCLS + c) * NP2PAD + NP2 + w] = 0u;
    }
  }
}

// ---------------------------------------------------------------------------
// Kernel 1 (v3): LDS-resident key row, parallel select, wave-synchronous NMS
// ---------------------------------------------------------------------------
__global__ __launch_bounds__(256) void perclass_v3(
    const float* __restrict__ loc, const float* __restrict__ conf,
    const float* __restrict__ prior, const u16* __restrict__ keys16,
    float* __restrict__ kept, float* __restrict__ cbox) {
  __shared__ __align__(16) u32 skrow[NP2PAD];  // 49152 B
  __shared__ u32 hist4[4 * 257];               // skewed 4-sub-copy histogram
  __shared__ u32 scnt[256], ssuf[256];
  __shared__ u64 keys[256];                    // (fullkey<<32) | ~prior_idx
  __shared__ u64 buf3[512];
  __shared__ float bx0[TOPK], bx1[TOPK], bx2[TOPK], bx3[TOPK], barea[TOPK], bscore[TOPK];
  __shared__ u32 s_sel, s_rem, s_cnt, s_cnt2, s_cnt3;

  const int tid = threadIdx.x;
  const int nwg = NB * NCLS;  // 2592, %8==0 -> bijective swizzle
  int i0 = blockIdx.x;
  int bc = (i0 & 7) * (nwg / 8) + (i0 >> 3);
  const int b = bc / NCLS, c = bc % NCLS;
  const size_t keptBase = (size_t)bc * TOPK;

  if (c == 0) {  // background class
    for (int k = tid; k < TOPK; k += 256) {
      kept[keptBase + k] = 0.f;
      float* bp = cbox + (keptBase + k) * 4;
      bp[0] = 0.f; bp[1] = 0.f; bp[2] = 0.f; bp[3] = 0.f;
    }
    return;
  }

  const float* confb = conf + (size_t)b * NP * NCLS + c;
  auto loadscore = [&](int p) -> float {
    float s = confb[(size_t)p * NCLS];
    return (s > CONF_THR) ? s : -1.0f;
  };

  const int sub = (tid & 3) * 257;

  auto clear_hist = [&]() {
    for (int j = tid; j < 4 * 257; j += 256) hist4[j] = 0u;
    __syncthreads();
  };

  // parallel select: find bin from top with cumulative >= Kin
  auto select_bin = [&](u32 Kin) {
    __syncthreads();  // atomics done
    scnt[tid] = hist4[tid] + hist4[257 + tid] + hist4[514 + tid] + hist4[771 + tid];
    __syncthreads();
    ssuf[tid] = scnt[tid];
    __syncthreads();
    for (int d = 1; d < 256; d <<= 1) {
      u32 add = (tid + d < 256) ? ssuf[tid + d] : 0u;
      __syncthreads();
      ssuf[tid] += add;
      __syncthreads();
    }
    u32 s = ssuf[tid], above = s - scnt[tid];
    if (s >= Kin && above < Kin) { s_sel = (u32)tid; s_rem = Kin - above; }
    __syncthreads();
  };

  // ---- stage global key row -> LDS, fused with pass-1 histogram ----
  u32 K = TOPK;
  clear_hist();
  {
    const u32* grow = (const u32*)keys16 + (size_t)bc * NP2PAD;
    const uint4* g4 = (const uint4*)grow;
    uint4* s4 = (uint4*)skrow;
    for (int i = tid; i < DW4; i += 256) {
      uint4 v = g4[i];
      s4[i] = v;
      u32 w0 = v.x, w1 = v.y, w2 = v.z, w3 = v.w;
      atomicAdd(&hist4[sub + ((w0 >> 8) & 255u)], 1u);
      atomicAdd(&hist4[sub + (w0 >> 24)], 1u);
      atomicAdd(&hist4[sub + ((w1 >> 8) & 255u)], 1u);
      atomicAdd(&hist4[sub + (w1 >> 24)], 1u);
      atomicAdd(&hist4[sub + ((w2 >> 8) & 255u)], 1u);
      atomicAdd(&hist4[sub + (w2 >> 24)], 1u);
      atomicAdd(&hist4[sub + ((w3 >> 8) & 255u)], 1u);
      atomicAdd(&hist4[sub + (w3 >> 24)], 1u);
    }
  }
  select_bin(K);
  const u32 b1 = s_sel; K = s_rem;
  // (pad zeros land in bin 0; all real keys >= 0x407F so bin 0 is never selected)

  // ---- pass 2: lo byte among hi-byte matches (LDS scan) ----
  clear_hist();
  for (int i = tid; i < NP2PAD; i += 256) {
    u32 v = skrow[i];
    u32 lo = v & 0xFFFFu, hi = v >> 16;
    if ((lo >> 8) == b1) atomicAdd(&hist4[sub + (lo & 255u)], 1u);
    if ((hi >> 8) == b1) atomicAdd(&hist4[sub + (hi & 255u)], 1u);
  }
  select_bin(K);
  const u32 pfx16 = (b1 << 8) | s_sel; K = s_rem;

  const bool fillMode = (pfx16 == NEGK16);
  u32 T;
  bool buffered = false;
  if (!fillMode) {
    // ---- pass 3: gather pfx16 matches w/ full keys; hist bits 15-8 ----
    if (tid == 0) s_cnt3 = 0;
    clear_hist();
    for (int i = tid; i < NP2PAD; i += 256) {
      u32 v = skrow[i];
      u32 lo = v & 0xFFFFu, hi = v >> 16;
      if (lo == pfx16) {
        int p = 2 * i;
        u32 kf = fkey(loadscore(p));
        u32 slot = atomicAdd(&s_cnt3, 1u);
        if (slot < 512u) buf3[slot] = ((u64)kf << 32) | (u32)(~(u32)p);
        atomicAdd(&hist4[sub + ((kf >> 8) & 255u)], 1u);
      }
      if (hi == pfx16) {
        int p = 2 * i + 1;
        u32 kf = fkey(loadscore(p));
        u32 slot = atomicAdd(&s_cnt3, 1u);
        if (slot < 512u) buf3[slot] = ((u64)kf << 32) | (u32)(~(u32)p);
        atomicAdd(&hist4[sub + ((kf >> 8) & 255u)], 1u);
      }
    }
    select_bin(K);
    const u32 b3 = s_sel; K = s_rem;
    buffered = (s_cnt3 <= 512u);  // uniform

    // ---- pass 4: low byte ----
    clear_hist();
    if (buffered) {
      u32 n3 = s_cnt3;
      for (u32 i = tid; i < n3; i += 256) {
        u32 kf = (u32)(buf3[i] >> 32);
        if (((kf >> 8) & 255u) == b3) atomicAdd(&hist4[sub + (kf & 255u)], 1u);
      }
    } else {
      for (int i = tid; i < NP2PAD; i += 256) {
        u32 v = skrow[i];
        u32 lo = v & 0xFFFFu, hi = v >> 16;
        if (lo == pfx16) {
          u32 kf = fkey(loadscore(2 * i));
          if (((kf >> 8) & 255u) == b3) atomicAdd(&hist4[sub + (kf & 255u)], 1u);
        }
        if (hi == pfx16) {
          u32 kf = fkey(loadscore(2 * i + 1));
          if (((kf >> 8) & 255u) == b3) atomicAdd(&hist4[sub + (kf & 255u)], 1u);
        }
      }
    }
    select_bin(K);
    T = (pfx16 << 16) | (b3 << 8) | s_sel; K = s_rem;
  } else {
    T = NEGKEY;
  }

  // ---- gather G strictly-greater + ties (LDS scan) ----
  const u32 G = TOPK - K;
  keys[tid] = 0;
  if (tid == 0) { s_cnt = 0; s_cnt2 = 0; }
  __syncthreads();
  for (int i = tid; i < NP2PAD; i += 256) {
    u32 v = skrow[i];
    u32 k16[2] = {v & 0xFFFFu, v >> 16};
#pragma unroll
    for (int h = 0; h < 2; ++h) {
      int p = 2 * i + h;
      if (k16[h] > pfx16) {
        u32 kf = fkey(loadscore(p));
        u32 slot = atomicAdd(&s_cnt, 1u);
        keys[slot] = ((u64)kf << 32) | (u32)(~(u32)p);
      } else if (!fillMode && !buffered && k16[h] == pfx16) {
        u32 kf = fkey(loadscore(p));
        if (kf > T) {
          u32 slot = atomicAdd(&s_cnt, 1u);
          keys[slot] = ((u64)kf << 32) | (u32)(~(u32)p);
        } else if (kf == T) {
          u32 t2 = atomicAdd(&s_cnt2, 1u);
          u32 slot = G + t2;
          if (slot < 256u) keys[slot] = ((u64)kf << 32) | (u32)(~(u32)p);
        }
      }
    }
  }
  if (buffered) {
    __syncthreads();
    u32 n3 = s_cnt3;
    for (u32 i = tid; i < n3; i += 256) {
      u64 e = buf3[i];
      u32 kf = (u32)(e >> 32);
      if (kf > T) {
        u32 slot = atomicAdd(&s_cnt, 1u);
        keys[slot] = e;
      } else if (kf == T) {
        u32 t2 = atomicAdd(&s_cnt2, 1u);
        u32 slot = G + t2;
        if (slot < 256u) keys[slot] = e;
      }
    }
  }
  __syncthreads();
  if (fillMode) {  // inert filler entries (score -1, prior 0)
    for (int k = (int)G + tid; k < TOPK; k += 256)
      keys[k] = ((u64)T << 32) | 0xFFFFFFFFull;
    __syncthreads();
  }

  // ---- bitonic sort 256 u64 descending ----
  for (u32 kk = 2; kk <= 256; kk <<= 1) {
    for (u32 j = kk >> 1; j > 0; j >>= 1) {
      u32 ixj = (u32)tid ^ j;
      if (ixj > (u32)tid) {
        u64 a = keys[tid], bb = keys[ixj];
        bool asc = (tid & kk) != 0;
        if (asc ? (a > bb) : (a < bb)) { keys[tid] = bb; keys[ixj] = a; }
      }
      __syncthreads();
    }
  }

  // ---- decode 200 candidates; write boxes to global + LDS ----
  if (tid < TOPK) {
    u64 e = keys[tid];
    float myscore = unfkey((u32)(e >> 32));
    int p = (int)(~(u32)e);
    const float* lp = loc + ((size_t)b * NP + p) * 4;
    const float* pp = prior + (size_t)p * 4;
    const float* vp = prior + (size_t)NP * 4 + (size_t)p * 4;
    float p0 = pp[0], p1 = pp[1], p2 = pp[2], p3 = pp[3];
    float pw = p2 - p0, ph = p3 - p1;
    float pcx = (p0 + p2) * 0.5f, pcy = (p1 + p3) * 0.5f;
    float cx = vp[0] * lp[0] * pw + pcx;
    float cy = vp[1] * lp[1] * ph + pcy;
    float w = expf(vp[2] * lp[2]) * pw;
    float h = expf(vp[3] * lp[3]) * ph;
    float rx0 = cx - w * 0.5f, ry0 = cy - h * 0.5f;
    float rx1 = cx + w * 0.5f, ry1 = cy + h * 0.5f;
    float rarea = fmaxf(rx1 - rx0, 0.f) * fmaxf(ry1 - ry0, 0.f);
    bx0[tid] = rx0; bx1[tid] = ry0; bx2[tid] = rx1; bx3[tid] = ry1;
    barea[tid] = rarea; bscore[tid] = myscore;
    float* bp = cbox + (keptBase + tid) * 4;
    bp[0] = rx0; bp[1] = ry0; bp[2] = rx1; bp[3] = ry1;
  }
  __syncthreads();

  // ---- greedy NMS: single wave, zero barriers (4 candidates per lane) ----
  if (tid < 64) {
    const int lane = tid;
    float sx0[4], sy0[4], sx1[4], sy1[4], sar[4], ssc[4];
    int sup[4] = {0, 0, 0, 0};
    int keepm = 0;
#pragma unroll
    for (int s = 0; s < 4; ++s) {
      int cc = s * 64 + lane;
      if (cc < TOPK) {
        sx0[s] = bx0[cc]; sy0[s] = bx1[cc]; sx1[s] = bx2[cc]; sy1[s] = bx3[cc];
        sar[s] = barea[cc]; ssc[s] = bscore[cc];
      } else {
        sx0[s] = 0.f; sy0[s] = 0.f; sx1[s] = 0.f; sy1[s] = 0.f;
        sar[s] = 0.f; ssc[s] = -1.f;  // never kept
      }
    }
#pragma unroll
    for (int s = 0; s < 4; ++s) {
      for (int j = 0; j < 64; ++j) {  // candidate i = s*64+j, sequential
        float sc_i = __shfl(ssc[s], j);
        int sup_i = __shfl(sup[s], j);
        if (sc_i > CONF_THR && sup_i == 0) {  // wave-uniform branch
          if (j == lane) keepm |= 1 << s;
          float a0 = __shfl(sx0[s], j), a1 = __shfl(sy0[s], j);
          float a2 = __shfl(sx1[s], j), a3 = __shfl(sy1[s], j);
          float aa = __shfl(sar[s], j);
#pragma unroll
          for (int s2 = 0; s2 < 4; ++s2) {
            float xx1 = fmaxf(a0, sx0[s2]), yy1 = fmaxf(a1, sy0[s2]);
            float xx2 = fminf(a2, sx1[s2]), yy2 = fminf(a3, sy1[s2]);
            float inter = fmaxf(xx2 - xx1, 0.f) * fmaxf(yy2 - yy1, 0.f);
            float uni = aa + sar[s2] - inter;
            if (inter / fmaxf(uni, 1e-10f) > NMS_THR) sup[s2] = 1;
          }
        }
      }
    }
#pragma unroll
    for (int s = 0; s < 4; ++s) {
      int cc = s * 64 + lane;
      if (cc < TOPK)
        kept[keptBase + cc] = ((keepm >> s) & 1) ? ssc[s] : 0.f;
    }
  }
}

// ---------------------------------------------------------------------------
// Kernel 1 (fallback, proven): strided scan version for small ws_size
// ---------------------------------------------------------------------------
__global__ __launch_bounds__(256) void perclass_fallback(
    const float* __restrict__ loc, const float* __restrict__ conf,
    const float* __restrict__ prior, float* __restrict__ kept,
    float* __restrict__ cbox) {
  __shared__ u16 skey[NP];
  __shared__ unsigned int hist[256];
  __shared__ u64 keys[256];
  __shared__ float bx0[TOPK], bx1[TOPK], bx2[TOPK], bx3[TOPK];
  __shared__ float barea[TOPK], bscore[TOPK];
  __shared__ unsigned char sup[TOPK], keepf[TOPK];
  __shared__ unsigned int s_sel, s_rem, s_cnt, s_cnt2;

  const int tid = threadIdx.x;
  const int nwg = NB * NCLS;
  int i0 = blockIdx.x;
  int bc = (i0 & 7) * (nwg / 8) + (i0 >> 3);
  const int b = bc / NCLS, c = bc % NCLS;
  const size_t keptBase = (size_t)bc * TOPK;

  if (c == 0) {
    for (int k = tid; k < TOPK; k += 256) {
      kept[keptBase + k] = 0.f;
      float* bp = cbox + (keptBase + k) * 4;
      bp[0] = 0.f; bp[1] = 0.f; bp[2] = 0.f; bp[3] = 0.f;
    }
    return;
  }

  const float* confb = conf + (size_t)b * NP * NCLS + c;
  auto loadscore = [&](int p) -> float {
    float s = confb[(size_t)p * NCLS];
    return (s > CONF_THR) ? s : -1.0f;
  };

  for (int p = tid; p < NP; p += 256)
    skey[p] = (u16)(fkey(loadscore(p)) >> 16);
  __syncthreads();

  auto select_bin = [&](u32 Kin) {
    if (tid == 0) {
      u32 rem = Kin;
      int bin = 255;
      for (; bin > 0; --bin) {
        u32 cnt = hist[bin];
        if (cnt >= rem) break;
        rem -= cnt;
      }
      s_sel = (u32)bin; s_rem = rem;
    }
    __syncthreads();
  };

  u32 K = TOPK;
  hist[tid] = 0; __syncthreads();
  for (int p = tid; p < NP; p += 256) atomicAdd(&hist[skey[p] >> 8], 1u);
  __syncthreads();
  select_bin(K);
  u32 pfx16 = s_sel << 8; K = s_rem;

  hist[tid] = 0; __syncthreads();
  {
    u32 hb = pfx16 >> 8;
    for (int p = tid; p < NP; p += 256) {
      u16 v = skey[p];
      if ((u32)(v >> 8) == hb) atomicAdd(&hist[v & 255], 1u);
    }
  }
  __syncthreads();
  select_bin(K);
  pfx16 |= s_sel; K = s_rem;

  const bool fillMode = (pfx16 == NEGK16);
  u32 T;
  if (!fillMode) {
    u32 pfull = pfx16 << 16;
    hist[tid] = 0; __syncthreads();
    for (int p = tid; p < NP; p += 256) {
      if ((u32)skey[p] == pfx16) {
        u32 kf = fkey(loadscore(p));
        atomicAdd(&hist[(kf >> 8) & 255], 1u);
      }
    }
    __syncthreads();
    select_bin(K);
    pfull |= s_sel << 8; K = s_rem;

    hist[tid] = 0; __syncthreads();
    for (int p = tid; p < NP; p += 256) {
      if ((u32)skey[p] == pfx16) {
        u32 kf = fkey(loadscore(p));
        if ((kf >> 8) == (pfull >> 8)) atomicAdd(&hist[kf & 255], 1u);
      }
    }
    __syncthreads();
    select_bin(K);
    T = pfull | s_sel; K = s_rem;
  } else {
    T = NEGKEY;
  }

  const u32 G = TOPK - K;
  keys[tid] = 0;
  if (tid == 0) { s_cnt = 0; s_cnt2 = 0; }
  __syncthreads();
  for (int p = tid; p < NP; p += 256) {
    u32 v = skey[p];
    if (v > pfx16) {
      float s = loadscore(p);
      u32 slot = atomicAdd(&s_cnt, 1u);
      keys[slot] = ((u64)fkey(s) << 32) | (u32)(~(u32)p);
    } else if (!fillMode && v == pfx16) {
      float s = loadscore(p);
      u32 kf = fkey(s);
      if (kf > T) {
        u32 slot = atomicAdd(&s_cnt, 1u);
        keys[slot] = ((u64)kf << 32) | (u32)(~(u32)p);
      } else if (kf == T) {
        u32 t2 = atomicAdd(&s_cnt2, 1u);
        u32 slot = G + t2;
        if (slot < 256u) keys[slot] = ((u64)kf << 32) | (u32)(~(u32)p);
      }
    }
  }
  __syncthreads();
  if (fillMode) {
    for (int k = (int)G + tid; k < TOPK; k += 256)
      keys[k] = ((u64)T << 32) | 0xFFFFFFFFull;
  }
  __syncthreads();

  for (u32 kk = 2; kk <= 256; kk <<= 1) {
    for (u32 j = kk >> 1; j > 0; j >>= 1) {
      u32 ixj = (u32)tid ^ j;
      if (ixj > (u32)tid) {
        u64 a = keys[tid], bb = keys[ixj];
        bool asc = (tid & kk) != 0;
        if (asc ? (a > bb) : (a < bb)) { keys[tid] = bb; keys[ixj] = a; }
      }
      __syncthreads();
    }
  }

  if (tid < TOPK) {
    u64 e = keys[tid];
    float s = unfkey((u32)(e >> 32));
    int p = (int)(~(u32)e);
    const float* lp = loc + ((size_t)b * NP + p) * 4;
    const float* pp = prior + (size_t)p * 4;
    const float* vp = prior + (size_t)NP * 4 + (size_t)p * 4;
    float p0 = pp[0], p1 = pp[1], p2 = pp[2], p3 = pp[3];
    float pw = p2 - p0, ph = p3 - p1;
    float pcx = (p0 + p2) * 0.5f, pcy = (p1 + p3) * 0.5f;
    float cx = vp[0] * lp[0] * pw + pcx;
    float cy = vp[1] * lp[1] * ph + pcy;
    float w = expf(vp[2] * lp[2]) * pw;
    float h = expf(vp[3] * lp[3]) * ph;
    float x0 = cx - w * 0.5f, y0 = cy - h * 0.5f;
    float x1 = cx + w * 0.5f, y1 = cy + h * 0.5f;
    bx0[tid] = x0; bx1[tid] = y0; bx2[tid] = x1; bx3[tid] = y1;
    barea[tid] = fmaxf(x1 - x0, 0.f) * fmaxf(y1 - y0, 0.f);
    bscore[tid] = s;
    sup[tid] = 0;
    keepf[tid] = 0;
  }
  __syncthreads();

  for (int i = 0; i < TOPK; ++i) {
    bool kept_i = (bscore[i] > CONF_THR) && (sup[i] == 0);
    __syncthreads();
    if (kept_i) {
      if (tid < TOPK) {
        float xx1 = fmaxf(bx0[i], bx0[tid]);
        float yy1 = fmaxf(bx1[i], bx1[tid]);
        float xx2 = fminf(bx2[i], bx2[tid]);
        float yy2 = fminf(bx3[i], bx3[tid]);
        float inter = fmaxf(xx2 - xx1, 0.f) * fmaxf(yy2 - yy1, 0.f);
        float uni = barea[i] + barea[tid] - inter;
        float iou = inter / fmaxf(uni, 1e-10f);
        if (iou > NMS_THR) sup[tid] = 1;
      }
      if (tid == 0) keepf[i] = 1;
    }
    __syncthreads();
  }

  if (tid < TOPK) {
    kept[keptBase + tid] = keepf[tid] ? bscore[tid] : 0.f;
    float* bp = cbox + (keptBase + tid) * 4;
    bp[0] = bx0[tid]; bp[1] = bx1[tid]; bp[2] = bx2[tid]; bp[3] = bx3[tid];
  }
}

// ---------------------------------------------------------------------------
// Kernel 2: per-batch top-200 over C*TOPK kept scores -> output rows
// ---------------------------------------------------------------------------
__global__ __launch_bounds__(256) void final_topk(
    const float* __restrict__ kept, const float* __restrict__ cbox,
    float* __restrict__ out) {
  __shared__ unsigned int hist[256];
  __shared__ u64 keys[256];
  __shared__ unsigned int s_sel, s_rem, s_cnt, s_cnt2;

  const int tid = threadIdx.x;
  const int b = blockIdx.x;
  const float* sc = kept + (size_t)b * NFLAT;

  auto select_bin = [&](u32 Kin) {
    if (tid == 0) {
      u32 rem = Kin;
      int bin = 255;
      for (; bin > 0; --bin) {
        u32 cnt = hist[bin];
        if (cnt >= rem) break;
        rem -= cnt;
      }
      s_sel = (u32)bin; s_rem = rem;
    }
    __syncthreads();
  };

  u32 pfx = 0;
  u32 K = KEEPK;
  for (int shift = 24; shift >= 0; shift -= 8) {
    hist[tid] = 0; __syncthreads();
    u32 himask = (shift == 24) ? 0u : (0xFFFFFFFFu << (shift + 8));
    for (int p = tid; p < NFLAT; p += 256) {
      u32 kf = fkey(sc[p]);
      if ((kf & himask) == pfx) atomicAdd(&hist[(kf >> shift) & 255], 1u);
    }
    __syncthreads();
    select_bin(K);
    pfx |= s_sel << shift; K = s_rem;
  }

  const bool fill2 = (pfx == fkey(0.0f));
  const u32 G = KEEPK - K;
  keys[tid] = 0;
  if (tid == 0) { s_cnt = 0; s_cnt2 = 0; }
  __syncthreads();
  for (int p = tid; p < NFLAT; p += 256) {
    u32 kf = fkey(sc[p]);
    if (kf > pfx) {
      u32 slot = atomicAdd(&s_cnt, 1u);
      keys[slot] = ((u64)kf << 32) | (u32)(~(u32)p);
    } else if (!fill2 && kf == pfx) {
      u32 t2 = atomicAdd(&s_cnt2, 1u);
      u32 slot = G + t2;
      if (slot < 256u) keys[slot] = ((u64)kf << 32) | (u32)(~(u32)p);
    }
  }
  __syncthreads();
  if (fill2) {
    for (int k = (int)G + tid; k < KEEPK; k += 256)
      keys[k] = ((u64)pfx << 32) | 0xFFFFFFFFull;
  }
  __syncthreads();

  for (u32 kk = 2; kk <= 256; kk <<= 1) {
    for (u32 j = kk >> 1; j > 0; j >>= 1) {
      u32 ixj = (u32)tid ^ j;
      if (ixj > (u32)tid) {
        u64 a = keys[tid], bb = keys[ixj];
        bool asc = (tid & kk) != 0;
        if (asc ? (a > bb) : (a < bb)) { keys[tid] = bb; keys[ixj] = a; }
      }
      __syncthreads();
    }
  }

  if (tid < KEEPK) {
    u64 e = keys[tid];
    float s = unfkey((u32)(e >> 32));
    u32 fi = ~(u32)e;
    float r0 = 0.f, r1 = 0.f, r2 = 0.f, r3 = 0.f, r4 = 0.f, r5 = 0.f, r6 = 0.f;
    if (s > 0.f) {
      r0 = (float)b;
      r1 = (float)(fi / TOPK);
      r2 = s;
      const float* bp = cbox + ((size_t)b * NFLAT + fi) * 4;
      r3 = bp[0]; r4 = bp[1]; r5 = bp[2]; r6 = bp[3];
    }
    float* op = out + ((size_t)b * KEEPK + tid) * 7;
    op[0] = r0; op[1] = r1; op[2] = r2; op[3] = r3;
    op[4] = r4; op[5] = r5; op[6] = r6;
  }
}

extern "C" void kernel_launch(void* const* d_in, const int* in_sizes, int n_in,
                              void* d_out, int out_size, void* d_ws, size_t ws_size,
                              hipStream_t stream) {
  const float* loc = (const float*)d_in[0];
  const float* conf = (const float*)d_in[1];
  const float* prior = (const float*)d_in[2];
  float* out = (float*)d_out;

  float* kept = (float*)d_ws;                     // NB*NCLS*TOPK floats
  float* cbox = kept + (size_t)NB * NCLS * TOPK;  // NB*NCLS*TOPK*4 floats
  const size_t baseBytes = (size_t)NB * NCLS * TOPK * 5 * sizeof(float);   // 10.37 MB
  const size_t keysBytes = (size_t)NB * NCLS * NPPAD * sizeof(u16);        // 127.4 MB

  if (ws_size >= baseBytes + keysBytes) {
    u16* keys16 = (u16*)((char*)d_ws + baseBytes);
    build_keys<<<dim3(NB * NCHUNK), dim3(256), 0, stream>>>(conf, keys16);
    perclass_v3<<<dim3(NB * NCLS), dim3(256), 0, stream>>>(loc, conf, prior,
                                                           keys16, kept, cbox);
  } else {
    perclass_fallback<<<dim3(NB * NCLS), dim3(256), 0, stream>>>(loc, conf,
                                                                 prior, kept, cbox);
  }
  final_topk<<<dim3(NB), dim3(256), 0, stream>>>(kept, cbox, out);
}

// Round 10
// 666.851 us; speedup vs baseline: 1.2187x; 1.2187x over previous
//
#include <hip/hip_runtime.h>
#include <stdint.h>

typedef uint32_t u32;
typedef uint64_t u64;
typedef uint16_t u16;

#define NCLS 81
#define TOPK 200
#define KEEPK 200
#define CONF_THR 0.01f
#define NMS_THR 0.45f
#define NB 32
#define NP 24564
#define NPPAD 24576            /* row padded to 16B multiple */
#define NP2 (NP / 2)           /* 12282 */
#define NP2PAD (NPPAD / 2)     /* 12288 u32 words */
#define DW4 (NP2PAD / 4)       /* 3072 uint4 per row */
#define NFLAT (NCLS * TOPK)    /* 16200 */
#define NPCHUNK 256
#define NCHUNK ((NP + NPCHUNK - 1) / NPCHUNK) /* 96 */

// order-preserving map float -> u32 (ascending)
__device__ __forceinline__ u32 fkey(float f) {
  u32 u = __float_as_uint(f);
  return (u & 0x80000000u) ? ~u : (u | 0x80000000u);
}
__device__ __forceinline__ float unfkey(u32 k) {
  u32 u = (k & 0x80000000u) ? (k & 0x7FFFFFFFu) : ~k;
  return __uint_as_float(u);
}

// fkey(-1.0f) = 0x407FFFFF; top 16 bits = 0x407F
#define NEGKEY 0x407FFFFFu
#define NEGK16 0x407Fu

// ---------------------------------------------------------------------------
// Kernel 0: coalesced conf read -> thresholded u16 keys, transposed [B][C][NPPAD]
// ---------------------------------------------------------------------------
__global__ __launch_bounds__(256) void build_keys(const float* __restrict__ conf,
                                                  u16* __restrict__ keys16) {
  __shared__ u16 tile[NCLS][NPCHUNK + 2];  // 81 x 258 u16

  const int tid = threadIdx.x;
  const int blk = blockIdx.x;
  const int b = blk / NCHUNK, chunk = blk % NCHUNK;
  const int p0 = chunk * NPCHUNK;
  const int cnt = min(NPCHUNK, NP - p0);  // 256 or 244 (even)
  const int tot = cnt * NCLS;
  const float* src = conf + ((size_t)b * NP + p0) * NCLS;  // 16B-aligned

  for (int f4 = tid * 4; f4 < tot; f4 += 256 * 4) {
    if (f4 + 3 < tot) {
      float4 v = *reinterpret_cast<const float4*>(src + f4);
      float vv[4] = {v.x, v.y, v.z, v.w};
#pragma unroll
      for (int j = 0; j < 4; ++j) {
        int f = f4 + j;
        int pi = f / NCLS, c = f - pi * NCLS;
        float s = vv[j];
        s = (s > CONF_THR) ? s : -1.0f;
        tile[c][pi] = (u16)(fkey(s) >> 16);
      }
    } else {
      for (int f = f4; f < tot; ++f) {
        int pi = f / NCLS, c = f - pi * NCLS;
        float s = src[f];
        s = (s > CONF_THR) ? s : -1.0f;
        tile[c][pi] = (u16)(fkey(s) >> 16);
      }
    }
  }
  __syncthreads();

  const int halves = cnt >> 1;  // 128 or 122
  u32* dst32 = (u32*)keys16;
  if (halves == 128) {
    for (int i = tid; i < NCLS * 128; i += 256) {
      int c = i >> 7, w = i & 127;
      u32 lo = tile[c][2 * w], hi = tile[c][2 * w + 1];
      size_t rowbase = ((size_t)b * NCLS + c) * NP2PAD + (p0 >> 1);
      dst32[rowbase + w] = lo | (hi << 16);
    }
  } else {
    for (int i = tid; i < NCLS * halves; i += 256) {
      int c = i / halves, w = i - c * halves;
      u32 lo = tile[c][2 * w], hi = tile[c][2 * w + 1];
      size_t rowbase = ((size_t)b * NCLS + c) * NP2PAD + (p0 >> 1);
      dst32[rowbase + w] = lo | (hi << 16);
    }
    // last chunk: zero the 6 pad words per class (pad keys sort below all real)
    for (int i = tid; i < NCLS * 6; i += 256) {
      int c = i / 6, w = i - c * 6;
      dst32[((size_t)b * NCLS + c) * NP2PAD + NP2 + w] = 0u;
    }
  }
}

// ---------------------------------------------------------------------------
// Kernel 1 (v4): global key-row scans (high occupancy) + parallel select +
//                skewed histograms + barrier-free wave-redundant NMS
// ---------------------------------------------------------------------------
__global__ __launch_bounds__(256) void perclass_v4(
    const float* __restrict__ loc, const float* __restrict__ conf,
    const float* __restrict__ prior, const u16* __restrict__ keys16,
    float* __restrict__ kept, float* __restrict__ cbox) {
  __shared__ u32 hist4[4 * 257];  // 4 skewed sub-histograms (bin b, copy k -> bank (b+k)%32)
  __shared__ u32 scnt[256], ssuf[256];
  __shared__ u64 keys[256];       // (fullkey<<32) | ~prior_idx
  __shared__ u64 buf3[512];       // pfx16-matching elements with full keys
  __shared__ float bx0[TOPK], bx1[TOPK], bx2[TOPK], bx3[TOPK], barea[TOPK], bscore[TOPK];
  __shared__ u32 s_sel, s_rem, s_cnt, s_cnt2, s_cnt3;

  const int tid = threadIdx.x;
  const int nwg = NB * NCLS;  // 2592, %8==0 -> bijective XCD swizzle
  int i0 = blockIdx.x;
  int bc = (i0 & 7) * (nwg / 8) + (i0 >> 3);
  const int b = bc / NCLS, c = bc % NCLS;
  const size_t keptBase = (size_t)bc * TOPK;

  if (c == 0) {  // background class
    for (int k = tid; k < TOPK; k += 256) {
      kept[keptBase + k] = 0.f;
      float* bp = cbox + (keptBase + k) * 4;
      bp[0] = 0.f; bp[1] = 0.f; bp[2] = 0.f; bp[3] = 0.f;
    }
    return;
  }

  const u32* krow32 = (const u32*)keys16 + (size_t)bc * NP2PAD;  // 16B-aligned
  const float* confb = conf + (size_t)b * NP * NCLS + c;
  auto loadscore = [&](int p) -> float {
    float s = confb[(size_t)p * NCLS];
    return (s > CONF_THR) ? s : -1.0f;
  };

  const int sub = (tid & 3) * 257;

  auto clear_hist = [&]() {
    for (int j = tid; j < 4 * 257; j += 256) hist4[j] = 0u;
    __syncthreads();
  };

  // parallel select: find bin (from top) where cumulative count reaches Kin
  auto select_bin = [&](u32 Kin) {
    __syncthreads();  // histogram atomics done
    scnt[tid] = hist4[tid] + hist4[257 + tid] + hist4[514 + tid] + hist4[771 + tid];
    __syncthreads();
    ssuf[tid] = scnt[tid];
    __syncthreads();
    for (int d = 1; d < 256; d <<= 1) {
      u32 add = (tid + d < 256) ? ssuf[tid + d] : 0u;
      __syncthreads();
      ssuf[tid] += add;
      __syncthreads();
    }
    u32 s = ssuf[tid], above = s - scnt[tid];
    if (s >= Kin && above < Kin) { s_sel = (u32)tid; s_rem = Kin - above; }
    __syncthreads();
  };

  // ---- pass 1: hi byte of 16-bit key (uint4 global loads) ----
  u32 K = TOPK;
  clear_hist();
  {
    const uint4* g4 = (const uint4*)krow32;
    for (int i = tid; i < DW4; i += 256) {
      uint4 v = g4[i];
      atomicAdd(&hist4[sub + ((v.x >> 8) & 255u)], 1u);
      atomicAdd(&hist4[sub + (v.x >> 24)], 1u);
      atomicAdd(&hist4[sub + ((v.y >> 8) & 255u)], 1u);
      atomicAdd(&hist4[sub + (v.y >> 24)], 1u);
      atomicAdd(&hist4[sub + ((v.z >> 8) & 255u)], 1u);
      atomicAdd(&hist4[sub + (v.z >> 24)], 1u);
      atomicAdd(&hist4[sub + ((v.w >> 8) & 255u)], 1u);
      atomicAdd(&hist4[sub + (v.w >> 24)], 1u);
    }
  }
  select_bin(K);
  const u32 b1 = s_sel; K = s_rem;
  // pad zeros land in bin 0; real keys >= 0x407F so bin 0 never selected

  // ---- pass 2: lo byte among hi-byte matches ----
  clear_hist();
  for (int i = tid; i < NP2PAD; i += 256) {
    u32 v = krow32[i];
    u32 lo = v & 0xFFFFu, hi = v >> 16;
    if ((lo >> 8) == b1) atomicAdd(&hist4[sub + (lo & 255u)], 1u);
    if ((hi >> 8) == b1) atomicAdd(&hist4[sub + (hi & 255u)], 1u);
  }
  select_bin(K);
  const u32 pfx16 = (b1 << 8) | s_sel; K = s_rem;

  const bool fillMode = (pfx16 == NEGK16);
  u32 T;
  bool buffered = false;
  if (!fillMode) {
    // ---- pass 3: gather pfx16 matches w/ full keys into buf3; hist bits 15-8
    if (tid == 0) s_cnt3 = 0;
    clear_hist();
    for (int i = tid; i < NP2PAD; i += 256) {
      u32 v = krow32[i];
      u32 lo = v & 0xFFFFu, hi = v >> 16;
      if (lo == pfx16) {
        int p = 2 * i;
        u32 kf = fkey(loadscore(p));
        u32 slot = atomicAdd(&s_cnt3, 1u);
        if (slot < 512u) buf3[slot] = ((u64)kf << 32) | (u32)(~(u32)p);
        atomicAdd(&hist4[sub + ((kf >> 8) & 255u)], 1u);
      }
      if (hi == pfx16) {
        int p = 2 * i + 1;
        u32 kf = fkey(loadscore(p));
        u32 slot = atomicAdd(&s_cnt3, 1u);
        if (slot < 512u) buf3[slot] = ((u64)kf << 32) | (u32)(~(u32)p);
        atomicAdd(&hist4[sub + ((kf >> 8) & 255u)], 1u);
      }
    }
    select_bin(K);
    const u32 b3 = s_sel; K = s_rem;
    buffered = (s_cnt3 <= 512u);  // uniform (shared)

    // ---- pass 4: low byte ----
    clear_hist();
    if (buffered) {
      u32 n3 = s_cnt3;
      for (u32 i = tid; i < n3; i += 256) {
        u32 kf = (u32)(buf3[i] >> 32);
        if (((kf >> 8) & 255u) == b3) atomicAdd(&hist4[sub + (kf & 255u)], 1u);
      }
    } else {
      for (int i = tid; i < NP2PAD; i += 256) {
        u32 v = krow32[i];
        u32 lo = v & 0xFFFFu, hi = v >> 16;
        if (lo == pfx16) {
          u32 kf = fkey(loadscore(2 * i));
          if (((kf >> 8) & 255u) == b3) atomicAdd(&hist4[sub + (kf & 255u)], 1u);
        }
        if (hi == pfx16) {
          u32 kf = fkey(loadscore(2 * i + 1));
          if (((kf >> 8) & 255u) == b3) atomicAdd(&hist4[sub + (kf & 255u)], 1u);
        }
      }
    }
    select_bin(K);
    T = (pfx16 << 16) | (b3 << 8) | s_sel; K = s_rem;
  } else {
    T = NEGKEY;
  }

  // ---- gather G strictly-greater + ties ----
  const u32 G = TOPK - K;
  keys[tid] = 0;  // pad sorts last
  if (tid == 0) { s_cnt = 0; s_cnt2 = 0; }
  __syncthreads();
  for (int i = tid; i < NP2PAD; i += 256) {
    u32 v = krow32[i];
    u32 k16[2] = {v & 0xFFFFu, v >> 16};
#pragma unroll
    for (int h = 0; h < 2; ++h) {
      int p = 2 * i + h;
      if (k16[h] > pfx16) {
        u32 kf = fkey(loadscore(p));
        u32 slot = atomicAdd(&s_cnt, 1u);
        keys[slot] = ((u64)kf << 32) | (u32)(~(u32)p);
      } else if (!fillMode && !buffered && k16[h] == pfx16) {
        u32 kf = fkey(loadscore(p));
        if (kf > T) {
          u32 slot = atomicAdd(&s_cnt, 1u);
          keys[slot] = ((u64)kf << 32) | (u32)(~(u32)p);
        } else if (kf == T) {
          u32 t2 = atomicAdd(&s_cnt2, 1u);
          u32 slot = G + t2;
          if (slot < 256u) keys[slot] = ((u64)kf << 32) | (u32)(~(u32)p);
        }
      }
    }
  }
  if (buffered) {
    __syncthreads();
    u32 n3 = s_cnt3;
    for (u32 i = tid; i < n3; i += 256) {
      u64 e = buf3[i];
      u32 kf = (u32)(e >> 32);
      if (kf > T) {
        u32 slot = atomicAdd(&s_cnt, 1u);
        keys[slot] = e;
      } else if (kf == T) {
        u32 t2 = atomicAdd(&s_cnt2, 1u);
        u32 slot = G + t2;
        if (slot < 256u) keys[slot] = e;
      }
    }
  }
  __syncthreads();
  if (fillMode) {  // inert filler entries (score -1, prior 0)
    for (int k = (int)G + tid; k < TOPK; k += 256)
      keys[k] = ((u64)T << 32) | 0xFFFFFFFFull;
    __syncthreads();
  }

  // ---- bitonic sort 256 u64 descending (score desc, prior asc via ~p) ----
  for (u32 kk = 2; kk <= 256; kk <<= 1) {
    for (u32 j = kk >> 1; j > 0; j >>= 1) {
      u32 ixj = (u32)tid ^ j;
      if (ixj > (u32)tid) {
        u64 a = keys[tid], bb = keys[ixj];
        bool asc = (tid & kk) != 0;
        if (asc ? (a > bb) : (a < bb)) { keys[tid] = bb; keys[ixj] = a; }
      }
      __syncthreads();
    }
  }

  // ---- decode 200 candidates; write boxes to global + LDS ----
  if (tid < TOPK) {
    u64 e = keys[tid];
    float myscore = unfkey((u32)(e >> 32));
    int p = (int)(~(u32)e);
    const float* lp = loc + ((size_t)b * NP + p) * 4;
    const float* pp = prior + (size_t)p * 4;
    const float* vp = prior + (size_t)NP * 4 + (size_t)p * 4;
    float p0 = pp[0], p1 = pp[1], p2 = pp[2], p3 = pp[3];
    float pw = p2 - p0, ph = p3 - p1;
    float pcx = (p0 + p2) * 0.5f, pcy = (p1 + p3) * 0.5f;
    float cx = vp[0] * lp[0] * pw + pcx;
    float cy = vp[1] * lp[1] * ph + pcy;
    float w = expf(vp[2] * lp[2]) * pw;
    float h = expf(vp[3] * lp[3]) * ph;
    float rx0 = cx - w * 0.5f, ry0 = cy - h * 0.5f;
    float rx1 = cx + w * 0.5f, ry1 = cy + h * 0.5f;
    float rarea = fmaxf(rx1 - rx0, 0.f) * fmaxf(ry1 - ry0, 0.f);
    bx0[tid] = rx0; bx1[tid] = ry0; bx2[tid] = rx1; bx3[tid] = ry1;
    barea[tid] = rarea; bscore[tid] = myscore;
    float* bp = cbox + (keptBase + tid) * 4;
    bp[0] = rx0; bp[1] = ry0; bp[2] = rx1; bp[3] = ry1;
  }
  __syncthreads();

  // ---- greedy NMS: every wave redundantly computes (zero barriers);
  //      wave w writes candidate group w.
  {
    const int lane = tid & 63;
    const int wv = tid >> 6;
    float sx0[4], sy0[4], sx1[4], sy1[4], sar[4], ssc[4];
    int sup[4] = {0, 0, 0, 0};
    int keepm = 0;
#pragma unroll
    for (int s = 0; s < 4; ++s) {
      int cc = s * 64 + lane;
      if (cc < TOPK) {
        sx0[s] = bx0[cc]; sy0[s] = bx1[cc]; sx1[s] = bx2[cc]; sy1[s] = bx3[cc];
        sar[s] = barea[cc]; ssc[s] = bscore[cc];
      } else {
        sx0[s] = 0.f; sy0[s] = 0.f; sx1[s] = 0.f; sy1[s] = 0.f;
        sar[s] = 0.f; ssc[s] = -1.f;  // never kept
      }
    }
#pragma unroll
    for (int s = 0; s < 4; ++s) {
      for (int j = 0; j < 64; ++j) {  // candidate i = s*64+j, in order
        float sc_i = __shfl(ssc[s], j);
        int sup_i = __shfl(sup[s], j);
        if (sc_i > CONF_THR && sup_i == 0) {  // wave-uniform branch
          if (j == lane) keepm |= 1 << s;
          float a0 = __shfl(sx0[s], j), a1 = __shfl(sy0[s], j);
          float a2 = __shfl(sx1[s], j), a3 = __shfl(sy1[s], j);
          float aa = __shfl(sar[s], j);
#pragma unroll
          for (int s2 = 0; s2 < 4; ++s2) {
            float xx1 = fmaxf(a0, sx0[s2]), yy1 = fmaxf(a1, sy0[s2]);
            float xx2 = fminf(a2, sx1[s2]), yy2 = fminf(a3, sy1[s2]);
            float inter = fmaxf(xx2 - xx1, 0.f) * fmaxf(yy2 - yy1, 0.f);
            float uni = aa + sar[s2] - inter;
            if (inter / fmaxf(uni, 1e-10f) > NMS_THR) sup[s2] = 1;
          }
        }
      }
    }
    // wave wv writes its group (all waves computed identical results)
    int cc = wv * 64 + lane;  // == tid
    if (cc < TOPK)
      kept[keptBase + cc] = ((keepm >> wv) & 1) ? ssc[wv] : 0.f;
  }
}

// ---------------------------------------------------------------------------
// Kernel 1 (fallback, proven): strided scan version for small ws_size
// ---------------------------------------------------------------------------
__global__ __launch_bounds__(256) void perclass_fallback(
    const float* __restrict__ loc, const float* __restrict__ conf,
    const float* __restrict__ prior, float* __restrict__ kept,
    float* __restrict__ cbox) {
  __shared__ u16 skey[NP];
  __shared__ unsigned int hist[256];
  __shared__ u64 keys[256];
  __shared__ float bx0[TOPK], bx1[TOPK], bx2[TOPK], bx3[TOPK];
  __shared__ float barea[TOPK], bscore[TOPK];
  __shared__ unsigned char sup[TOPK], keepf[TOPK];
  __shared__ unsigned int s_sel, s_rem, s_cnt, s_cnt2;

  const int tid = threadIdx.x;
  const int nwg = NB * NCLS;
  int i0 = blockIdx.x;
  int bc = (i0 & 7) * (nwg / 8) + (i0 >> 3);
  const int b = bc / NCLS, c = bc % NCLS;
  const size_t keptBase = (size_t)bc * TOPK;

  if (c == 0) {
    for (int k = tid; k < TOPK; k += 256) {
      kept[keptBase + k] = 0.f;
      float* bp = cbox + (keptBase + k) * 4;
      bp[0] = 0.f; bp[1] = 0.f; bp[2] = 0.f; bp[3] = 0.f;
    }
    return;
  }

  const float* confb = conf + (size_t)b * NP * NCLS + c;
  auto loadscore = [&](int p) -> float {
    float s = confb[(size_t)p * NCLS];
    return (s > CONF_THR) ? s : -1.0f;
  };

  for (int p = tid; p < NP; p += 256)
    skey[p] = (u16)(fkey(loadscore(p)) >> 16);
  __syncthreads();

  auto select_bin = [&](u32 Kin) {
    if (tid == 0) {
      u32 rem = Kin;
      int bin = 255;
      for (; bin > 0; --bin) {
        u32 cnt = hist[bin];
        if (cnt >= rem) break;
        rem -= cnt;
      }
      s_sel = (u32)bin; s_rem = rem;
    }
    __syncthreads();
  };

  u32 K = TOPK;
  hist[tid] = 0; __syncthreads();
  for (int p = tid; p < NP; p += 256) atomicAdd(&hist[skey[p] >> 8], 1u);
  __syncthreads();
  select_bin(K);
  u32 pfx16 = s_sel << 8; K = s_rem;

  hist[tid] = 0; __syncthreads();
  {
    u32 hb = pfx16 >> 8;
    for (int p = tid; p < NP; p += 256) {
      u16 v = skey[p];
      if ((u32)(v >> 8) == hb) atomicAdd(&hist[v & 255], 1u);
    }
  }
  __syncthreads();
  select_bin(K);
  pfx16 |= s_sel; K = s_rem;

  const bool fillMode = (pfx16 == NEGK16);
  u32 T;
  if (!fillMode) {
    u32 pfull = pfx16 << 16;
    hist[tid] = 0; __syncthreads();
    for (int p = tid; p < NP; p += 256) {
      if ((u32)skey[p] == pfx16) {
        u32 kf = fkey(loadscore(p));
        atomicAdd(&hist[(kf >> 8) & 255], 1u);
      }
    }
    __syncthreads();
    select_bin(K);
    pfull |= s_sel << 8; K = s_rem;

    hist[tid] = 0; __syncthreads();
    for (int p = tid; p < NP; p += 256) {
      if ((u32)skey[p] == pfx16) {
        u32 kf = fkey(loadscore(p));
        if ((kf >> 8) == (pfull >> 8)) atomicAdd(&hist[kf & 255], 1u);
      }
    }
    __syncthreads();
    select_bin(K);
    T = pfull | s_sel; K = s_rem;
  } else {
    T = NEGKEY;
  }

  const u32 G = TOPK - K;
  keys[tid] = 0;
  if (tid == 0) { s_cnt = 0; s_cnt2 = 0; }
  __syncthreads();
  for (int p = tid; p < NP; p += 256) {
    u32 v = skey[p];
    if (v > pfx16) {
      float s = loadscore(p);
      u32 slot = atomicAdd(&s_cnt, 1u);
      keys[slot] = ((u64)fkey(s) << 32) | (u32)(~(u32)p);
    } else if (!fillMode && v == pfx16) {
      float s = loadscore(p);
      u32 kf = fkey(s);
      if (kf > T) {
        u32 slot = atomicAdd(&s_cnt, 1u);
        keys[slot] = ((u64)kf << 32) | (u32)(~(u32)p);
      } else if (kf == T) {
        u32 t2 = atomicAdd(&s_cnt2, 1u);
        u32 slot = G + t2;
        if (slot < 256u) keys[slot] = ((u64)kf << 32) | (u32)(~(u32)p);
      }
    }
  }
  __syncthreads();
  if (fillMode) {
    for (int k = (int)G + tid; k < TOPK; k += 256)
      keys[k] = ((u64)T << 32) | 0xFFFFFFFFull;
  }
  __syncthreads();

  for (u32 kk = 2; kk <= 256; kk <<= 1) {
    for (u32 j = kk >> 1; j > 0; j >>= 1) {
      u32 ixj = (u32)tid ^ j;
      if (ixj > (u32)tid) {
        u64 a = keys[tid], bb = keys[ixj];
        bool asc = (tid & kk) != 0;
        if (asc ? (a > bb) : (a < bb)) { keys[tid] = bb; keys[ixj] = a; }
      }
      __syncthreads();
    }
  }

  if (tid < TOPK) {
    u64 e = keys[tid];
    float s = unfkey((u32)(e >> 32));
    int p = (int)(~(u32)e);
    const float* lp = loc + ((size_t)b * NP + p) * 4;
    const float* pp = prior + (size_t)p * 4;
    const float* vp = prior + (size_t)NP * 4 + (size_t)p * 4;
    float p0 = pp[0], p1 = pp[1], p2 = pp[2], p3 = pp[3];
    float pw = p2 - p0, ph = p3 - p1;
    float pcx = (p0 + p2) * 0.5f, pcy = (p1 + p3) * 0.5f;
    float cx = vp[0] * lp[0] * pw + pcx;
    float cy = vp[1] * lp[1] * ph + pcy;
    float w = expf(vp[2] * lp[2]) * pw;
    float h = expf(vp[3] * lp[3]) * ph;
    float x0 = cx - w * 0.5f, y0 = cy - h * 0.5f;
    float x1 = cx + w * 0.5f, y1 = cy + h * 0.5f;
    bx0[tid] = x0; bx1[tid] = y0; bx2[tid] = x1; bx3[tid] = y1;
    barea[tid] = fmaxf(x1 - x0, 0.f) * fmaxf(y1 - y0, 0.f);
    bscore[tid] = s;
    sup[tid] = 0;
    keepf[tid] = 0;
  }
  __syncthreads();

  for (int i = 0; i < TOPK; ++i) {
    bool kept_i = (bscore[i] > CONF_THR) && (sup[i] == 0);
    __syncthreads();
    if (kept_i) {
      if (tid < TOPK) {
        float xx1 = fmaxf(bx0[i], bx0[tid]);
        float yy1 = fmaxf(bx1[i], bx1[tid]);
        float xx2 = fminf(bx2[i], bx2[tid]);
        float yy2 = fminf(bx3[i], bx3[tid]);
        float inter = fmaxf(xx2 - xx1, 0.f) * fmaxf(yy2 - yy1, 0.f);
        float uni = barea[i] + barea[tid] - inter;
        float iou = inter / fmaxf(uni, 1e-10f);
        if (iou > NMS_THR) sup[tid] = 1;
      }
      if (tid == 0) keepf[i] = 1;
    }
    __syncthreads();
  }

  if (tid < TOPK) {
    kept[keptBase + tid] = keepf[tid] ? bscore[tid] : 0.f;
    float* bp = cbox + (keptBase + tid) * 4;
    bp[0] = bx0[tid]; bp[1] = bx1[tid]; bp[2] = bx2[tid]; bp[3] = bx3[tid];
  }
}

// ---------------------------------------------------------------------------
// Kernel 2: per-batch top-200 over C*TOPK kept scores -> output rows
// ---------------------------------------------------------------------------
__global__ __launch_bounds__(256) void final_topk(
    const float* __restrict__ kept, const float* __restrict__ cbox,
    float* __restrict__ out) {
  __shared__ unsigned int hist[256];
  __shared__ u64 keys[256];
  __shared__ unsigned int s_sel, s_rem, s_cnt, s_cnt2;

  const int tid = threadIdx.x;
  const int b = blockIdx.x;
  const float* sc = kept + (size_t)b * NFLAT;

  auto select_bin = [&](u32 Kin) {
    if (tid == 0) {
      u32 rem = Kin;
      int bin = 255;
      for (; bin > 0; --bin) {
        u32 cnt = hist[bin];
        if (cnt >= rem) break;
        rem -= cnt;
      }
      s_sel = (u32)bin; s_rem = rem;
    }
    __syncthreads();
  };

  u32 pfx = 0;
  u32 K = KEEPK;
  for (int shift = 24; shift >= 0; shift -= 8) {
    hist[tid] = 0; __syncthreads();
    u32 himask = (shift == 24) ? 0u : (0xFFFFFFFFu << (shift + 8));
    for (int p = tid; p < NFLAT; p += 256) {
      u32 kf = fkey(sc[p]);
      if ((kf & himask) == pfx) atomicAdd(&hist[(kf >> shift) & 255], 1u);
    }
    __syncthreads();
    select_bin(K);
    pfx |= s_sel << shift; K = s_rem;
  }

  const bool fill2 = (pfx == fkey(0.0f));
  const u32 G = KEEPK - K;
  keys[tid] = 0;
  if (tid == 0) { s_cnt = 0; s_cnt2 = 0; }
  __syncthreads();
  for (int p = tid; p < NFLAT; p += 256) {
    u32 kf = fkey(sc[p]);
    if (kf > pfx) {
      u32 slot = atomicAdd(&s_cnt, 1u);
      keys[slot] = ((u64)kf << 32) | (u32)(~(u32)p);
    } else if (!fill2 && kf == pfx) {
      u32 t2 = atomicAdd(&s_cnt2, 1u);
      u32 slot = G + t2;
      if (slot < 256u) keys[slot] = ((u64)kf << 32) | (u32)(~(u32)p);
    }
  }
  __syncthreads();
  if (fill2) {
    for (int k = (int)G + tid; k < KEEPK; k += 256)
      keys[k] = ((u64)pfx << 32) | 0xFFFFFFFFull;
  }
  __syncthreads();

  for (u32 kk = 2; kk <= 256; kk <<= 1) {
    for (u32 j = kk >> 1; j > 0; j >>= 1) {
      u32 ixj = (u32)tid ^ j;
      if (ixj > (u32)tid) {
        u64 a = keys[tid], bb = keys[ixj];
        bool asc = (tid & kk) != 0;
        if (asc ? (a > bb) : (a < bb)) { keys[tid] = bb; keys[ixj] = a; }
      }
      __syncthreads();
    }
  }

  if (tid < KEEPK) {
    u64 e = keys[tid];
    float s = unfkey((u32)(e >> 32));
    u32 fi = ~(u32)e;
    float r0 = 0.f, r1 = 0.f, r2 = 0.f, r3 = 0.f, r4 = 0.f, r5 = 0.f, r6 = 0.f;
    if (s > 0.f) {
      r0 = (float)b;
      r1 = (float)(fi / TOPK);
      r2 = s;
      const float* bp = cbox + ((size_t)b * NFLAT + fi) * 4;
      r3 = bp[0]; r4 = bp[1]; r5 = bp[2]; r6 = bp[3];
    }
    float* op = out + ((size_t)b * KEEPK + tid) * 7;
    op[0] = r0; op[1] = r1; op[2] = r2; op[3] = r3;
    op[4] = r4; op[5] = r5; op[6] = r6;
  }
}

extern "C" void kernel_launch(void* const* d_in, const int* in_sizes, int n_in,
                              void* d_out, int out_size, void* d_ws, size_t ws_size,
                              hipStream_t stream) {
  const float* loc = (const float*)d_in[0];
  const float* conf = (const float*)d_in[1];
  const float* prior = (const float*)d_in[2];
  float* out = (float*)d_out;

  float* kept = (float*)d_ws;                     // NB*NCLS*TOPK floats
  float* cbox = kept + (size_t)NB * NCLS * TOPK;  // NB*NCLS*TOPK*4 floats
  const size_t baseBytes = (size_t)NB * NCLS * TOPK * 5 * sizeof(float);   // 10.37 MB
  const size_t keysBytes = (size_t)NB * NCLS * NPPAD * sizeof(u16);        // 127.4 MB

  if (ws_size >= baseBytes + keysBytes) {
    u16* keys16 = (u16*)((char*)d_ws + baseBytes);
    build_keys<<<dim3(NB * NCHUNK), dim3(256), 0, stream>>>(conf, keys16);
    perclass_v4<<<dim3(NB * NCLS), dim3(256), 0, stream>>>(loc, conf, prior,
                                                           keys16, kept, cbox);
  } else {
    perclass_fallback<<<dim3(NB * NCLS), dim3(256), 0, stream>>>(loc, conf,
                                                                 prior, kept, cbox);
  }
  final_topk<<<dim3(NB), dim3(256), 0, stream>>>(kept, cbox, out);
}

// Round 11
// 459.634 us; speedup vs baseline: 1.7681x; 1.4508x over previous
//
#include <hip/hip_runtime.h>
#include <stdint.h>

typedef uint32_t u32;
typedef uint64_t u64;
typedef uint16_t u16;

#define NCLS 81
#define TOPK 200
#define KEEPK 200
#define CONF_THR 0.01f
#define NMS_THR 0.45f
#define NB 32
#define NP 24564
#define NPPAD 24576            /* row padded to 16B multiple */
#define NP2 (NP / 2)           /* 12282 */
#define NP2PAD (NPPAD / 2)     /* 12288 u32 words */
#define DW4 (NP2PAD / 4)       /* 3072 uint4 per row */
#define NFLAT (NCLS * TOPK)    /* 16200 */
#define NPCHUNK 256
#define NCHUNK ((NP + NPCHUNK - 1) / NPCHUNK) /* 96 */

// order-preserving map float -> u32 (ascending)
__device__ __forceinline__ u32 fkey(float f) {
  u32 u = __float_as_uint(f);
  return (u & 0x80000000u) ? ~u : (u | 0x80000000u);
}
__device__ __forceinline__ float unfkey(u32 k) {
  u32 u = (k & 0x80000000u) ? (k & 0x7FFFFFFFu) : ~k;
  return __uint_as_float(u);
}

// fkey(-1.0f) = 0x407FFFFF; top 16 bits = 0x407F
#define NEGKEY 0x407FFFFFu
#define NEGK16 0x407Fu

// ---------------------------------------------------------------------------
// Kernel 0: coalesced conf read -> thresholded u16 keys, transposed [B][C][NPPAD]
//           (incremental pi/cc index update: no per-element div/mod)
// ---------------------------------------------------------------------------
__global__ __launch_bounds__(256) void build_keys(const float* __restrict__ conf,
                                                  u16* __restrict__ keys16) {
  __shared__ u16 tile[NCLS][NPCHUNK + 2];  // 81 x 258 u16

  const int tid = threadIdx.x;
  const int blk = blockIdx.x;
  const int b = blk / NCHUNK, chunk = blk % NCHUNK;
  const int p0 = chunk * NPCHUNK;
  const int cnt = min(NPCHUNK, NP - p0);  // 256 or 244 (even)
  const int tot = cnt * NCLS;             // multiple of 4 (20736 or 19764)
  const float* src = conf + ((size_t)b * NP + p0) * NCLS;  // 16B-aligned

  // stride 1024 = 12*81 + 52
  int f = tid * 4;
  int pi = f / NCLS;
  int cc = f - pi * NCLS;
  for (; f + 3 < tot; f += 1024) {
    float4 v = *reinterpret_cast<const float4*>(src + f);
    float vv[4] = {v.x, v.y, v.z, v.w};
    int p2 = pi, c2 = cc;
#pragma unroll
    for (int j = 0; j < 4; ++j) {
      float s = vv[j];
      s = (s > CONF_THR) ? s : -1.0f;
      tile[c2][p2] = (u16)(fkey(s) >> 16);
      if (++c2 == NCLS) { c2 = 0; ++p2; }
    }
    cc += 52; pi += 12;
    if (cc >= NCLS) { cc -= NCLS; ++pi; }
  }
  __syncthreads();

  const int halves = cnt >> 1;  // 128 or 122
  u32* dst32 = (u32*)keys16;
  if (halves == 128) {
    for (int i = tid; i < NCLS * 128; i += 256) {
      int c = i >> 7, w = i & 127;
      u32 lo = tile[c][2 * w], hi = tile[c][2 * w + 1];
      size_t rowbase = ((size_t)b * NCLS + c) * NP2PAD + (p0 >> 1);
      dst32[rowbase + w] = lo | (hi << 16);
    }
  } else {
    for (int i = tid; i < NCLS * halves; i += 256) {
      int c = i / halves, w = i - c * halves;
      u32 lo = tile[c][2 * w], hi = tile[c][2 * w + 1];
      size_t rowbase = ((size_t)b * NCLS + c) * NP2PAD + (p0 >> 1);
      dst32[rowbase + w] = lo | (hi << 16);
    }
    // last chunk: zero the 6 pad words per class (pad keys sort below all real)
    for (int i = tid; i < NCLS * 6; i += 256) {
      int c = i / 6, w = i - c * 6;
      dst32[((size_t)b * NCLS + c) * NP2PAD + NP2 + w] = 0u;
    }
  }
}

// ---------------------------------------------------------------------------
// Kernel 1 (v5): 3 fused scans + parallel select + single-wave NMS
// ---------------------------------------------------------------------------
__global__ __launch_bounds__(256) void perclass_v5(
    const float* __restrict__ loc, const float* __restrict__ conf,
    const float* __restrict__ prior, const u16* __restrict__ keys16,
    float* __restrict__ kept, float* __restrict__ cbox) {
  __shared__ u32 hist4[4 * 257];  // 4 skewed sub-histograms
  __shared__ u32 scnt[256], ssuf[256];
  __shared__ u64 keys[256];       // (fullkey<<32) | ~prior_idx
  __shared__ u64 buf3[512];       // pfx16-matching elements with full keys
  __shared__ float bx0[TOPK], bx1[TOPK], bx2[TOPK], bx3[TOPK], barea[TOPK], bscore[TOPK];
  __shared__ u32 s_sel, s_rem, s_cnt, s_cnt2, s_cnt3;

  const int tid = threadIdx.x;
  const int nwg = NB * NCLS;  // 2592, %8==0 -> bijective XCD swizzle
  int i0 = blockIdx.x;
  int bc = (i0 & 7) * (nwg / 8) + (i0 >> 3);
  const int b = bc / NCLS, c = bc % NCLS;
  const size_t keptBase = (size_t)bc * TOPK;

  if (c == 0) {  // background class
    for (int k = tid; k < TOPK; k += 256) {
      kept[keptBase + k] = 0.f;
      float* bp = cbox + (keptBase + k) * 4;
      bp[0] = 0.f; bp[1] = 0.f; bp[2] = 0.f; bp[3] = 0.f;
    }
    return;
  }

  const u32* krow32 = (const u32*)keys16 + (size_t)bc * NP2PAD;  // 16B-aligned
  const uint4* g4 = (const uint4*)krow32;
  const float* confb = conf + (size_t)b * NP * NCLS + c;
  auto loadscore = [&](int p) -> float {
    float s = confb[(size_t)p * NCLS];
    return (s > CONF_THR) ? s : -1.0f;
  };

  const int sub = (tid & 3) * 257;

  auto clear_hist = [&]() {
    for (int j = tid; j < 4 * 257; j += 256) hist4[j] = 0u;
    __syncthreads();
  };

  // parallel select: find bin (from top) where cumulative count reaches Kin
  auto select_bin = [&](u32 Kin) {
    __syncthreads();  // histogram atomics done
    scnt[tid] = hist4[tid] + hist4[257 + tid] + hist4[514 + tid] + hist4[771 + tid];
    __syncthreads();
    ssuf[tid] = scnt[tid];
    __syncthreads();
    for (int d = 1; d < 256; d <<= 1) {
      u32 add = (tid + d < 256) ? ssuf[tid + d] : 0u;
      __syncthreads();
      ssuf[tid] += add;
      __syncthreads();
    }
    u32 s = ssuf[tid], above = s - scnt[tid];
    if (s >= Kin && above < Kin) { s_sel = (u32)tid; s_rem = Kin - above; }
    __syncthreads();
  };

  // ---- Scan A: hi-byte histogram (uint4) ----
  u32 K = TOPK;
  keys[tid] = 0;  // pad sorts last
  if (tid == 0) { s_cnt = 0; s_cnt2 = 0; s_cnt3 = 0; }
  clear_hist();   // barrier also covers keys/counter init
  for (int i = tid; i < DW4; i += 256) {
    uint4 v = g4[i];
    atomicAdd(&hist4[sub + ((v.x >> 8) & 255u)], 1u);
    atomicAdd(&hist4[sub + (v.x >> 24)], 1u);
    atomicAdd(&hist4[sub + ((v.y >> 8) & 255u)], 1u);
    atomicAdd(&hist4[sub + (v.y >> 24)], 1u);
    atomicAdd(&hist4[sub + ((v.z >> 8) & 255u)], 1u);
    atomicAdd(&hist4[sub + (v.z >> 24)], 1u);
    atomicAdd(&hist4[sub + ((v.w >> 8) & 255u)], 1u);
    atomicAdd(&hist4[sub + (v.w >> 24)], 1u);
  }
  select_bin(K);
  const u32 b1 = s_sel; K = s_rem;
  // pad zeros land in bin 0; real keys >= 0x407F so bin 0 never selected

  // ---- Scan B: lo-byte hist where hi==b1; collect hi>b1 into keys ----
  clear_hist();
  for (int i = tid; i < DW4; i += 256) {
    uint4 v = g4[i];
    u32 ws[4] = {v.x, v.y, v.z, v.w};
#pragma unroll
    for (int w = 0; w < 4; ++w) {
#pragma unroll
      for (int h = 0; h < 2; ++h) {
        u32 k16 = (h == 0) ? (ws[w] & 0xFFFFu) : (ws[w] >> 16);
        u32 hi8 = k16 >> 8;
        if (hi8 == b1) {
          atomicAdd(&hist4[sub + (k16 & 255u)], 1u);
        } else if (hi8 > b1) {
          int p = 2 * (4 * i + w) + h;
          u32 kf = fkey(loadscore(p));
          u32 slot = atomicAdd(&s_cnt, 1u);
          keys[slot] = ((u64)kf << 32) | (u32)(~(u32)p);
        }
      }
    }
  }
  select_bin(K);
  const u32 losel = s_sel;
  const u32 pfx16 = (b1 << 8) | losel; K = s_rem;

  const bool fillMode = (pfx16 == NEGK16);
  u32 T, G;
  if (!fillMode) {
    // ---- Scan C: among hi==b1: lo>losel -> keys; lo==losel -> buf3 + hist ----
    clear_hist();
    for (int i = tid; i < DW4; i += 256) {
      uint4 v = g4[i];
      u32 ws[4] = {v.x, v.y, v.z, v.w};
#pragma unroll
      for (int w = 0; w < 4; ++w) {
#pragma unroll
        for (int h = 0; h < 2; ++h) {
          u32 k16 = (h == 0) ? (ws[w] & 0xFFFFu) : (ws[w] >> 16);
          if ((k16 >> 8) == b1) {
            u32 lo8 = k16 & 255u;
            if (lo8 > losel) {
              int p = 2 * (4 * i + w) + h;
              u32 kf = fkey(loadscore(p));
              u32 slot = atomicAdd(&s_cnt, 1u);
              keys[slot] = ((u64)kf << 32) | (u32)(~(u32)p);
            } else if (lo8 == losel) {
              int p = 2 * (4 * i + w) + h;
              u32 kf = fkey(loadscore(p));
              u32 s3 = atomicAdd(&s_cnt3, 1u);
              if (s3 < 512u) buf3[s3] = ((u64)kf << 32) | (u32)(~(u32)p);
              atomicAdd(&hist4[sub + ((kf >> 8) & 255u)], 1u);
            }
          }
        }
      }
    }
    select_bin(K);
    const u32 b3 = s_sel; K = s_rem;
    const bool buffered = (s_cnt3 <= 512u);  // uniform (shared, post-barrier)

    // ---- pass 4: low byte of full key ----
    clear_hist();
    if (buffered) {
      u32 n3 = s_cnt3;
      for (u32 i = tid; i < n3; i += 256) {
        u32 kf = (u32)(buf3[i] >> 32);
        if (((kf >> 8) & 255u) == b3) atomicAdd(&hist4[sub + (kf & 255u)], 1u);
      }
    } else {  // rare exact fallback: rescan
      for (int i = tid; i < NP2PAD; i += 256) {
        u32 v = krow32[i];
#pragma unroll
        for (int h = 0; h < 2; ++h) {
          u32 k16 = (h == 0) ? (v & 0xFFFFu) : (v >> 16);
          if (k16 == pfx16) {
            u32 kf = fkey(loadscore(2 * i + h));
            if (((kf >> 8) & 255u) == b3) atomicAdd(&hist4[sub + (kf & 255u)], 1u);
          }
        }
      }
    }
    select_bin(K);
    T = (pfx16 << 16) | (b3 << 8) | s_sel; K = s_rem;
    G = TOPK - K;

    // ---- finalize boundary bin: strict-greater + ties ----
    if (buffered) {
      u32 n3 = s_cnt3;
      for (u32 i = tid; i < n3; i += 256) {
        u64 e = buf3[i];
        u32 kf = (u32)(e >> 32);
        if (kf > T) {
          keys[atomicAdd(&s_cnt, 1u)] = e;
        } else if (kf == T) {
          u32 t2 = atomicAdd(&s_cnt2, 1u);
          u32 sl = G + t2;
          if (sl < 256u) keys[sl] = e;
        }
      }
    } else {  // rare exact fallback
      for (int i = tid; i < NP2PAD; i += 256) {
        u32 v = krow32[i];
#pragma unroll
        for (int h = 0; h < 2; ++h) {
          u32 k16 = (h == 0) ? (v & 0xFFFFu) : (v >> 16);
          if (k16 == pfx16) {
            int p = 2 * i + h;
            u32 kf = fkey(loadscore(p));
            if (kf > T) {
              keys[atomicAdd(&s_cnt, 1u)] = ((u64)kf << 32) | (u32)(~(u32)p);
            } else if (kf == T) {
              u32 t2 = atomicAdd(&s_cnt2, 1u);
              u32 sl = G + t2;
              if (sl < 256u) keys[sl] = ((u64)kf << 32) | (u32)(~(u32)p);
            }
          }
        }
      }
    }
    __syncthreads();
  } else {
    T = NEGKEY;
    G = TOPK - K;  // scan-B keys writes complete (select_bin barrier)
    for (int k = (int)G + tid; k < TOPK; k += 256)
      keys[k] = ((u64)T << 32) | 0xFFFFFFFFull;  // inert filler
    __syncthreads();
  }

  // ---- bitonic sort 256 u64 descending (score desc, prior asc via ~p) ----
  for (u32 kk = 2; kk <= 256; kk <<= 1) {
    for (u32 j = kk >> 1; j > 0; j >>= 1) {
      u32 ixj = (u32)tid ^ j;
      if (ixj > (u32)tid) {
        u64 a = keys[tid], bb = keys[ixj];
        bool asc = (tid & kk) != 0;
        if (asc ? (a > bb) : (a < bb)) { keys[tid] = bb; keys[ixj] = a; }
      }
      __syncthreads();
    }
  }

  // ---- decode 200 candidates; write boxes to global + LDS ----
  if (tid < TOPK) {
    u64 e = keys[tid];
    float myscore = unfkey((u32)(e >> 32));
    int p = (int)(~(u32)e);
    const float* lp = loc + ((size_t)b * NP + p) * 4;
    const float* pp = prior + (size_t)p * 4;
    const float* vp = prior + (size_t)NP * 4 + (size_t)p * 4;
    float p0 = pp[0], p1 = pp[1], p2 = pp[2], p3 = pp[3];
    float pw = p2 - p0, ph = p3 - p1;
    float pcx = (p0 + p2) * 0.5f, pcy = (p1 + p3) * 0.5f;
    float cx = vp[0] * lp[0] * pw + pcx;
    float cy = vp[1] * lp[1] * ph + pcy;
    float w = expf(vp[2] * lp[2]) * pw;
    float h = expf(vp[3] * lp[3]) * ph;
    float rx0 = cx - w * 0.5f, ry0 = cy - h * 0.5f;
    float rx1 = cx + w * 0.5f, ry1 = cy + h * 0.5f;
    float rarea = fmaxf(rx1 - rx0, 0.f) * fmaxf(ry1 - ry0, 0.f);
    bx0[tid] = rx0; bx1[tid] = ry0; bx2[tid] = rx1; bx3[tid] = ry1;
    barea[tid] = rarea; bscore[tid] = myscore;
    float* bp = cbox + (keptBase + tid) * 4;
    bp[0] = rx0; bp[1] = ry0; bp[2] = rx1; bp[3] = ry1;
  }
  __syncthreads();

  // ---- greedy NMS: single wave, zero barriers (4 candidates per lane) ----
  if (tid < 64) {
    const int lane = tid;
    float sx0[4], sy0[4], sx1[4], sy1[4], sar[4], ssc[4];
    int sup[4] = {0, 0, 0, 0};
    int keepm = 0;
#pragma unroll
    for (int s = 0; s < 4; ++s) {
      int cc = s * 64 + lane;
      if (cc < TOPK) {
        sx0[s] = bx0[cc]; sy0[s] = bx1[cc]; sx1[s] = bx2[cc]; sy1[s] = bx3[cc];
        sar[s] = barea[cc]; ssc[s] = bscore[cc];
      } else {
        sx0[s] = 0.f; sy0[s] = 0.f; sx1[s] = 0.f; sy1[s] = 0.f;
        sar[s] = 0.f; ssc[s] = -1.f;  // never kept
      }
    }
#pragma unroll
    for (int s = 0; s < 4; ++s) {
      for (int j = 0; j < 64; ++j) {  // candidate i = s*64+j, in order
        float sc_i = __shfl(ssc[s], j);
        int sup_i = __shfl(sup[s], j);
        if (sc_i > CONF_THR && sup_i == 0) {  // wave-uniform branch
          if (j == lane) keepm |= 1 << s;
          float a0 = __shfl(sx0[s], j), a1 = __shfl(sy0[s], j);
          float a2 = __shfl(sx1[s], j), a3 = __shfl(sy1[s], j);
          float aa = __shfl(sar[s], j);
#pragma unroll
          for (int s2 = 0; s2 < 4; ++s2) {
            float xx1 = fmaxf(a0, sx0[s2]), yy1 = fmaxf(a1, sy0[s2]);
            float xx2 = fminf(a2, sx1[s2]), yy2 = fminf(a3, sy1[s2]);
            float inter = fmaxf(xx2 - xx1, 0.f) * fmaxf(yy2 - yy1, 0.f);
            float uni = aa + sar[s2] - inter;
            float iou = inter / fmaxf(uni, 1e-10f);
            if (iou > NMS_THR) sup[s2] = 1;
          }
        }
      }
    }
#pragma unroll
    for (int s = 0; s < 4; ++s) {
      int cc = s * 64 + lane;
      if (cc < TOPK)
        kept[keptBase + cc] = ((keepm >> s) & 1) ? ssc[s] : 0.f;
    }
  }
}

// ---------------------------------------------------------------------------
// Kernel 1 (fallback, proven): strided scan version for small ws_size
// ---------------------------------------------------------------------------
__global__ __launch_bounds__(256) void perclass_fallback(
    const float* __restrict__ loc, const float* __restrict__ conf,
    const float* __restrict__ prior, float* __restrict__ kept,
    float* __restrict__ cbox) {
  __shared__ u16 skey[NP];
  __shared__ unsigned int hist[256];
  __shared__ u64 keys[256];
  __shared__ float bx0[TOPK], bx1[TOPK], bx2[TOPK], bx3[TOPK];
  __shared__ float barea[TOPK], bscore[TOPK];
  __shared__ unsigned char sup[TOPK], keepf[TOPK];
  __shared__ unsigned int s_sel, s_rem, s_cnt, s_cnt2;

  const int tid = threadIdx.x;
  const int nwg = NB * NCLS;
  int i0 = blockIdx.x;
  int bc = (i0 & 7) * (nwg / 8) + (i0 >> 3);
  const int b = bc / NCLS, c = bc % NCLS;
  const size_t keptBase = (size_t)bc * TOPK;

  if (c == 0) {
    for (int k = tid; k < TOPK; k += 256) {
      kept[keptBase + k] = 0.f;
      float* bp = cbox + (keptBase + k) * 4;
      bp[0] = 0.f; bp[1] = 0.f; bp[2] = 0.f; bp[3] = 0.f;
    }
    return;
  }

  const float* confb = conf + (size_t)b * NP * NCLS + c;
  auto loadscore = [&](int p) -> float {
    float s = confb[(size_t)p * NCLS];
    return (s > CONF_THR) ? s : -1.0f;
  };

  for (int p = tid; p < NP; p += 256)
    skey[p] = (u16)(fkey(loadscore(p)) >> 16);
  __syncthreads();

  auto select_bin = [&](u32 Kin) {
    if (tid == 0) {
      u32 rem = Kin;
      int bin = 255;
      for (; bin > 0; --bin) {
        u32 cnt = hist[bin];
        if (cnt >= rem) break;
        rem -= cnt;
      }
      s_sel = (u32)bin; s_rem = rem;
    }
    __syncthreads();
  };

  u32 K = TOPK;
  hist[tid] = 0; __syncthreads();
  for (int p = tid; p < NP; p += 256) atomicAdd(&hist[skey[p] >> 8], 1u);
  __syncthreads();
  select_bin(K);
  u32 pfx16 = s_sel << 8; K = s_rem;

  hist[tid] = 0; __syncthreads();
  {
    u32 hb = pfx16 >> 8;
    for (int p = tid; p < NP; p += 256) {
      u16 v = skey[p];
      if ((u32)(v >> 8) == hb) atomicAdd(&hist[v & 255], 1u);
    }
  }
  __syncthreads();
  select_bin(K);
  pfx16 |= s_sel; K = s_rem;

  const bool fillMode = (pfx16 == NEGK16);
  u32 T;
  if (!fillMode) {
    u32 pfull = pfx16 << 16;
    hist[tid] = 0; __syncthreads();
    for (int p = tid; p < NP; p += 256) {
      if ((u32)skey[p] == pfx16) {
        u32 kf = fkey(loadscore(p));
        atomicAdd(&hist[(kf >> 8) & 255], 1u);
      }
    }
    __syncthreads();
    select_bin(K);
    pfull |= s_sel << 8; K = s_rem;

    hist[tid] = 0; __syncthreads();
    for (int p = tid; p < NP; p += 256) {
      if ((u32)skey[p] == pfx16) {
        u32 kf = fkey(loadscore(p));
        if ((kf >> 8) == (pfull >> 8)) atomicAdd(&hist[kf & 255], 1u);
      }
    }
    __syncthreads();
    select_bin(K);
    T = pfull | s_sel; K = s_rem;
  } else {
    T = NEGKEY;
  }

  const u32 G = TOPK - K;
  keys[tid] = 0;
  if (tid == 0) { s_cnt = 0; s_cnt2 = 0; }
  __syncthreads();
  for (int p = tid; p < NP; p += 256) {
    u32 v = skey[p];
    if (v > pfx16) {
      float s = loadscore(p);
      u32 slot = atomicAdd(&s_cnt, 1u);
      keys[slot] = ((u64)fkey(s) << 32) | (u32)(~(u32)p);
    } else if (!fillMode && v == pfx16) {
      float s = loadscore(p);
      u32 kf = fkey(s);
      if (kf > T) {
        u32 slot = atomicAdd(&s_cnt, 1u);
        keys[slot] = ((u64)kf << 32) | (u32)(~(u32)p);
      } else if (kf == T) {
        u32 t2 = atomicAdd(&s_cnt2, 1u);
        u32 slot = G + t2;
        if (slot < 256u) keys[slot] = ((u64)kf << 32) | (u32)(~(u32)p);
      }
    }
  }
  __syncthreads();
  if (fillMode) {
    for (int k = (int)G + tid; k < TOPK; k += 256)
      keys[k] = ((u64)T << 32) | 0xFFFFFFFFull;
  }
  __syncthreads();

  for (u32 kk = 2; kk <= 256; kk <<= 1) {
    for (u32 j = kk >> 1; j > 0; j >>= 1) {
      u32 ixj = (u32)tid ^ j;
      if (ixj > (u32)tid) {
        u64 a = keys[tid], bb = keys[ixj];
        bool asc = (tid & kk) != 0;
        if (asc ? (a > bb) : (a < bb)) { keys[tid] = bb; keys[ixj] = a; }
      }
      __syncthreads();
    }
  }

  if (tid < TOPK) {
    u64 e = keys[tid];
    float s = unfkey((u32)(e >> 32));
    int p = (int)(~(u32)e);
    const float* lp = loc + ((size_t)b * NP + p) * 4;
    const float* pp = prior + (size_t)p * 4;
    const float* vp = prior + (size_t)NP * 4 + (size_t)p * 4;
    float p0 = pp[0], p1 = pp[1], p2 = pp[2], p3 = pp[3];
    float pw = p2 - p0, ph = p3 - p1;
    float pcx = (p0 + p2) * 0.5f, pcy = (p1 + p3) * 0.5f;
    float cx = vp[0] * lp[0] * pw + pcx;
    float cy = vp[1] * lp[1] * ph + pcy;
    float w = expf(vp[2] * lp[2]) * pw;
    float h = expf(vp[3] * lp[3]) * ph;
    float x0 = cx - w * 0.5f, y0 = cy - h * 0.5f;
    float x1 = cx + w * 0.5f, y1 = cy + h * 0.5f;
    bx0[tid] = x0; bx1[tid] = y0; bx2[tid] = x1; bx3[tid] = y1;
    barea[tid] = fmaxf(x1 - x0, 0.f) * fmaxf(y1 - y0, 0.f);
    bscore[tid] = s;
    sup[tid] = 0;
    keepf[tid] = 0;
  }
  __syncthreads();

  for (int i = 0; i < TOPK; ++i) {
    bool kept_i = (bscore[i] > CONF_THR) && (sup[i] == 0);
    __syncthreads();
    if (kept_i) {
      if (tid < TOPK) {
        float xx1 = fmaxf(bx0[i], bx0[tid]);
        float yy1 = fmaxf(bx1[i], bx1[tid]);
        float xx2 = fminf(bx2[i], bx2[tid]);
        float yy2 = fminf(bx3[i], bx3[tid]);
        float inter = fmaxf(xx2 - xx1, 0.f) * fmaxf(yy2 - yy1, 0.f);
        float uni = barea[i] + barea[tid] - inter;
        float iou = inter / fmaxf(uni, 1e-10f);
        if (iou > NMS_THR) sup[tid] = 1;
      }
      if (tid == 0) keepf[i] = 1;
    }
    __syncthreads();
  }

  if (tid < TOPK) {
    kept[keptBase + tid] = keepf[tid] ? bscore[tid] : 0.f;
    float* bp = cbox + (keptBase + tid) * 4;
    bp[0] = bx0[tid]; bp[1] = bx1[tid]; bp[2] = bx2[tid]; bp[3] = bx3[tid];
  }
}

// ---------------------------------------------------------------------------
// Kernel 2: per-batch top-200 over C*TOPK kept scores -> output rows
// ---------------------------------------------------------------------------
__global__ __launch_bounds__(256) void final_topk(
    const float* __restrict__ kept, const float* __restrict__ cbox,
    float* __restrict__ out) {
  __shared__ unsigned int hist[256];
  __shared__ u64 keys[256];
  __shared__ unsigned int s_sel, s_rem, s_cnt, s_cnt2;

  const int tid = threadIdx.x;
  const int b = blockIdx.x;
  const float* sc = kept + (size_t)b * NFLAT;

  auto select_bin = [&](u32 Kin) {
    if (tid == 0) {
      u32 rem = Kin;
      int bin = 255;
      for (; bin > 0; --bin) {
        u32 cnt = hist[bin];
        if (cnt >= rem) break;
        rem -= cnt;
      }
      s_sel = (u32)bin; s_rem = rem;
    }
    __syncthreads();
  };

  u32 pfx = 0;
  u32 K = KEEPK;
  for (int shift = 24; shift >= 0; shift -= 8) {
    hist[tid] = 0; __syncthreads();
    u32 himask = (shift == 24) ? 0u : (0xFFFFFFFFu << (shift + 8));
    for (int p = tid; p < NFLAT; p += 256) {
      u32 kf = fkey(sc[p]);
      if ((kf & himask) == pfx) atomicAdd(&hist[(kf >> shift) & 255], 1u);
    }
    __syncthreads();
    select_bin(K);
    pfx |= s_sel << shift; K = s_rem;
  }

  const bool fill2 = (pfx == fkey(0.0f));
  const u32 G = KEEPK - K;
  keys[tid] = 0;
  if (tid == 0) { s_cnt = 0; s_cnt2 = 0; }
  __syncthreads();
  for (int p = tid; p < NFLAT; p += 256) {
    u32 kf = fkey(sc[p]);
    if (kf > pfx) {
      u32 slot = atomicAdd(&s_cnt, 1u);
      keys[slot] = ((u64)kf << 32) | (u32)(~(u32)p);
    } else if (!fill2 && kf == pfx) {
      u32 t2 = atomicAdd(&s_cnt2, 1u);
      u32 slot = G + t2;
      if (slot < 256u) keys[slot] = ((u64)kf << 32) | (u32)(~(u32)p);
    }
  }
  __syncthreads();
  if (fill2) {
    for (int k = (int)G + tid; k < KEEPK; k += 256)
      keys[k] = ((u64)pfx << 32) | 0xFFFFFFFFull;
  }
  __syncthreads();

  for (u32 kk = 2; kk <= 256; kk <<= 1) {
    for (u32 j = kk >> 1; j > 0; j >>= 1) {
      u32 ixj = (u32)tid ^ j;
      if (ixj > (u32)tid) {
        u64 a = keys[tid], bb = keys[ixj];
        bool asc = (tid & kk) != 0;
        if (asc ? (a > bb) : (a < bb)) { keys[tid] = bb; keys[ixj] = a; }
      }
      __syncthreads();
    }
  }

  if (tid < KEEPK) {
    u64 e = keys[tid];
    float s = unfkey((u32)(e >> 32));
    u32 fi = ~(u32)e;
    float r0 = 0.f, r1 = 0.f, r2 = 0.f, r3 = 0.f, r4 = 0.f, r5 = 0.f, r6 = 0.f;
    if (s > 0.f) {
      r0 = (float)b;
      r1 = (float)(fi / TOPK);
      r2 = s;
      const float* bp = cbox + ((size_t)b * NFLAT + fi) * 4;
      r3 = bp[0]; r4 = bp[1]; r5 = bp[2]; r6 = bp[3];
    }
    float* op = out + ((size_t)b * KEEPK + tid) * 7;
    op[0] = r0; op[1] = r1; op[2] = r2; op[3] = r3;
    op[4] = r4; op[5] = r5; op[6] = r6;
  }
}

extern "C" void kernel_launch(void* const* d_in, const int* in_sizes, int n_in,
                              void* d_out, int out_size, void* d_ws, size_t ws_size,
                              hipStream_t stream) {
  const float* loc = (const float*)d_in[0];
  const float* conf = (const float*)d_in[1];
  const float* prior = (const float*)d_in[2];
  float* out = (float*)d_out;

  float* kept = (float*)d_ws;                     // NB*NCLS*TOPK floats
  float* cbox = kept + (size_t)NB * NCLS * TOPK;  // NB*NCLS*TOPK*4 floats
  const size_t baseBytes = (size_t)NB * NCLS * TOPK * 5 * sizeof(float);   // 10.37 MB
  const size_t keysBytes = (size_t)NB * NCLS * NPPAD * sizeof(u16);        // 127.4 MB

  if (ws_size >= baseBytes + keysBytes) {
    u16* keys16 = (u16*)((char*)d_ws + baseBytes);
    build_keys<<<dim3(NB * NCHUNK), dim3(256), 0, stream>>>(conf, keys16);
    perclass_v5<<<dim3(NB * NCLS), dim3(256), 0, stream>>>(loc, conf, prior,
                                                           keys16, kept, cbox);
  } else {
    perclass_fallback<<<dim3(NB * NCLS), dim3(256), 0, stream>>>(loc, conf,
                                                                 prior, kept, cbox);
  }
  final_topk<<<dim3(NB), dim3(256), 0, stream>>>(kept, cbox, out);
}

// Round 12
// 437.719 us; speedup vs baseline: 1.8566x; 1.0501x over previous
//
#include <hip/hip_runtime.h>
#include <stdint.h>

typedef uint32_t u32;
typedef uint64_t u64;
typedef uint16_t u16;

#define NCLS 81
#define TOPK 200
#define KEEPK 200
#define CONF_THR 0.01f
#define NMS_THR 0.45f
#define NB 32
#define NP 24564
#define NPPAD 24576            /* row padded to 16B multiple */
#define NP2 (NP / 2)           /* 12282 */
#define NP2PAD (NPPAD / 2)     /* 12288 u32 words */
#define DW4 (NP2PAD / 4)       /* 3072 uint4 per row */
#define NFLAT (NCLS * TOPK)    /* 16200 */
#define NPCHUNK 256
#define NCHUNK ((NP + NPCHUNK - 1) / NPCHUNK) /* 96 */

// order-preserving map float -> u32 (ascending)
__device__ __forceinline__ u32 fkey(float f) {
  u32 u = __float_as_uint(f);
  return (u & 0x80000000u) ? ~u : (u | 0x80000000u);
}
__device__ __forceinline__ float unfkey(u32 k) {
  u32 u = (k & 0x80000000u) ? (k & 0x7FFFFFFFu) : ~k;
  return __uint_as_float(u);
}

// fkey(-1.0f) = 0x407FFFFF; top 16 bits = 0x407F
#define NEGKEY 0x407FFFFFu
#define NEGK16 0x407Fu

// ---------------------------------------------------------------------------
// Kernel 0: coalesced conf read -> thresholded u16 keys, transposed [B][C][NPPAD]
// ---------------------------------------------------------------------------
__global__ __launch_bounds__(256) void build_keys(const float* __restrict__ conf,
                                                  u16* __restrict__ keys16) {
  __shared__ u16 tile[NCLS][NPCHUNK + 2];  // 81 x 258 u16

  const int tid = threadIdx.x;
  const int blk = blockIdx.x;
  const int b = blk / NCHUNK, chunk = blk % NCHUNK;
  const int p0 = chunk * NPCHUNK;
  const int cnt = min(NPCHUNK, NP - p0);  // 256 or 244 (even)
  const int tot = cnt * NCLS;             // multiple of 4
  const float* src = conf + ((size_t)b * NP + p0) * NCLS;  // 16B-aligned

  // stride 1024 = 12*81 + 52
  int f = tid * 4;
  int pi = f / NCLS;
  int cc = f - pi * NCLS;
  for (; f + 3 < tot; f += 1024) {
    float4 v = *reinterpret_cast<const float4*>(src + f);
    float vv[4] = {v.x, v.y, v.z, v.w};
    int p2 = pi, c2 = cc;
#pragma unroll
    for (int j = 0; j < 4; ++j) {
      float s = vv[j];
      s = (s > CONF_THR) ? s : -1.0f;
      tile[c2][p2] = (u16)(fkey(s) >> 16);
      if (++c2 == NCLS) { c2 = 0; ++p2; }
    }
    cc += 52; pi += 12;
    if (cc >= NCLS) { cc -= NCLS; ++pi; }
  }
  __syncthreads();

  const int halves = cnt >> 1;  // 128 or 122
  u32* dst32 = (u32*)keys16;
  if (halves == 128) {
    for (int i = tid; i < NCLS * 128; i += 256) {
      int c = i >> 7, w = i & 127;
      u32 lo = tile[c][2 * w], hi = tile[c][2 * w + 1];
      size_t rowbase = ((size_t)b * NCLS + c) * NP2PAD + (p0 >> 1);
      dst32[rowbase + w] = lo | (hi << 16);
    }
  } else {
    for (int i = tid; i < NCLS * halves; i += 256) {
      int c = i / halves, w = i - c * halves;
      u32 lo = tile[c][2 * w], hi = tile[c][2 * w + 1];
      size_t rowbase = ((size_t)b * NCLS + c) * NP2PAD + (p0 >> 1);
      dst32[rowbase + w] = lo | (hi << 16);
    }
    for (int i = tid; i < NCLS * 6; i += 256) {  // zero pad words
      int c = i / 6, w = i - c * 6;
      dst32[((size_t)b * NCLS + c) * NP2PAD + NP2 + w] = 0u;
    }
  }
}

// ---------------------------------------------------------------------------
// Kernel 1 (v6): 11-bit first pass (low-conflict hist) + parallel selects
// ---------------------------------------------------------------------------
__global__ __launch_bounds__(256) void perclass_v6(
    const float* __restrict__ loc, const float* __restrict__ conf,
    const float* __restrict__ prior, const u16* __restrict__ keys16,
    float* __restrict__ kept, float* __restrict__ cbox) {
  __shared__ u32 histm[2048];   // aliased: 2048-bin / 8x33 32-bin / 4x257 256-bin
  __shared__ u32 ssuf[256];
  __shared__ u64 keys[256];     // (fullkey<<32) | ~prior_idx
  __shared__ u64 buf3[256];     // boundary-group elements with full keys
  __shared__ float bx0[TOPK], bx1[TOPK], bx2[TOPK], bx3[TOPK], barea[TOPK], bscore[TOPK];
  __shared__ u32 s_sel, s_rem, s_cnt, s_cnt2, s_cnt3;

  const int tid = threadIdx.x;
  const int nwg = NB * NCLS;  // 2592, %8==0 -> bijective XCD swizzle
  int i0 = blockIdx.x;
  int bc = (i0 & 7) * (nwg / 8) + (i0 >> 3);
  const int b = bc / NCLS, c = bc % NCLS;
  const size_t keptBase = (size_t)bc * TOPK;

  if (c == 0) {  // background class
    for (int k = tid; k < TOPK; k += 256) {
      kept[keptBase + k] = 0.f;
      float* bp = cbox + (keptBase + k) * 4;
      bp[0] = 0.f; bp[1] = 0.f; bp[2] = 0.f; bp[3] = 0.f;
    }
    return;
  }

  const u32* krow32 = (const u32*)keys16 + (size_t)bc * NP2PAD;  // 16B-aligned
  const uint4* g4 = (const uint4*)krow32;
  const float* confb = conf + (size_t)b * NP * NCLS + c;
  auto loadscore = [&](int p) -> float {
    float s = confb[(size_t)p * NCLS];
    return (s > CONF_THR) ? s : -1.0f;
  };

  // ---- Scan A: 11-bit histogram (bits 15..5 of u16 key), single copy ----
  u32 K = TOPK;
  keys[tid] = 0;
  if (tid == 0) { s_cnt = 0; s_cnt2 = 0; s_cnt3 = 0; }
  for (int j = tid; j < 2048; j += 256) histm[j] = 0u;
  __syncthreads();
  for (int i = tid; i < DW4; i += 256) {
    uint4 v = g4[i];
    atomicAdd(&histm[(v.x & 0xFFFFu) >> 5], 1u);
    atomicAdd(&histm[v.x >> 21], 1u);
    atomicAdd(&histm[(v.y & 0xFFFFu) >> 5], 1u);
    atomicAdd(&histm[v.y >> 21], 1u);
    atomicAdd(&histm[(v.z & 0xFFFFu) >> 5], 1u);
    atomicAdd(&histm[v.z >> 21], 1u);
    atomicAdd(&histm[(v.w & 0xFFFFu) >> 5], 1u);
    atomicAdd(&histm[v.w >> 21], 1u);
  }
  // two-level parallel select over 2048 bins
  {
    __syncthreads();
    u32 g[8], loc = 0;
    const u32 base = tid * 8;
#pragma unroll
    for (int j = 0; j < 8; ++j) { g[j] = histm[base + j]; loc += g[j]; }
    ssuf[tid] = loc;
    __syncthreads();
    for (int d = 1; d < 256; d <<= 1) {
      u32 add = (tid + d < 256) ? ssuf[tid + d] : 0u;
      __syncthreads();
      ssuf[tid] += add;
      __syncthreads();
    }
    u32 s = ssuf[tid], above = s - loc;
    if (s >= K && above < K) {
      u32 run = above;
#pragma unroll
      for (int j = 7; j >= 0; --j) {
        u32 h = g[j];
        if (run + h >= K) { s_sel = base + j; s_rem = K - run; break; }
        run += h;
      }
    }
    __syncthreads();
  }
  const u32 bin11 = s_sel; K = s_rem;
  // pad zeros -> bin 0; real keys >= 0x407F -> bin >= 515, never selected

  // ---- Scan B: 5-bit hist (8 skew copies) inside bin11; collect above ----
  for (int j = tid; j < 8 * 33; j += 256) histm[j] = 0u;
  __syncthreads();
  {
    const u32 sub8 = (tid & 7) * 33;
    for (int i = tid; i < DW4; i += 256) {
      uint4 v = g4[i];
      u32 ws[4] = {v.x, v.y, v.z, v.w};
#pragma unroll
      for (int w = 0; w < 4; ++w) {
#pragma unroll
        for (int h = 0; h < 2; ++h) {
          u32 k16 = (h == 0) ? (ws[w] & 0xFFFFu) : (ws[w] >> 16);
          u32 b11 = k16 >> 5;
          if (b11 == bin11) {
            atomicAdd(&histm[sub8 + (k16 & 31u)], 1u);
          } else if (b11 > bin11) {
            int p = 2 * (4 * i + w) + h;
            u32 kf = fkey(loadscore(p));
            u32 slot = atomicAdd(&s_cnt, 1u);
            keys[slot] = ((u64)kf << 32) | (u32)(~(u32)p);
          }
        }
      }
    }
  }
  // select over 32 bins
  {
    __syncthreads();
    u32 cntv = 0;
    if (tid < 32) {
#pragma unroll
      for (int cp = 0; cp < 8; ++cp) cntv += histm[cp * 33 + tid];
    }
    ssuf[tid] = cntv;
    __syncthreads();
    for (int d = 1; d < 32; d <<= 1) {
      u32 add = (tid + d < 32) ? ssuf[tid + d] : 0u;
      __syncthreads();
      ssuf[tid] += add;
      __syncthreads();
    }
    if (tid < 32) {
      u32 s = ssuf[tid], above = s - cntv;
      if (s >= K && above < K) { s_sel = (u32)tid; s_rem = K - above; }
    }
    __syncthreads();
  }
  const u32 sel5 = s_sel;
  const u32 pfx16 = (bin11 << 5) | sel5; K = s_rem;

  const bool fillMode = (pfx16 == NEGK16);
  u32 T, G;
  const int sub4 = (tid & 3) * 257;

  auto select256s = [&](u32 Kin) {
    __syncthreads();
    u32 cntv = histm[tid] + histm[257 + tid] + histm[514 + tid] + histm[771 + tid];
    ssuf[tid] = cntv;
    __syncthreads();
    for (int d = 1; d < 256; d <<= 1) {
      u32 add = (tid + d < 256) ? ssuf[tid + d] : 0u;
      __syncthreads();
      ssuf[tid] += add;
      __syncthreads();
    }
    u32 s = ssuf[tid], above = s - cntv;
    if (s >= Kin && above < Kin) { s_sel = (u32)tid; s_rem = Kin - above; }
    __syncthreads();
  };

  if (!fillMode) {
    // ---- Scan C: inside bin11: lo5>sel5 -> keys; lo5==sel5 -> buf3 + hist ----
    for (int j = tid; j < 4 * 257; j += 256) histm[j] = 0u;
    __syncthreads();
    for (int i = tid; i < DW4; i += 256) {
      uint4 v = g4[i];
      u32 ws[4] = {v.x, v.y, v.z, v.w};
#pragma unroll
      for (int w = 0; w < 4; ++w) {
#pragma unroll
        for (int h = 0; h < 2; ++h) {
          u32 k16 = (h == 0) ? (ws[w] & 0xFFFFu) : (ws[w] >> 16);
          if ((k16 >> 5) == bin11) {
            u32 lo5 = k16 & 31u;
            if (lo5 > sel5) {
              int p = 2 * (4 * i + w) + h;
              u32 kf = fkey(loadscore(p));
              u32 slot = atomicAdd(&s_cnt, 1u);
              keys[slot] = ((u64)kf << 32) | (u32)(~(u32)p);
            } else if (lo5 == sel5) {
              int p = 2 * (4 * i + w) + h;
              u32 kf = fkey(loadscore(p));
              u32 s3 = atomicAdd(&s_cnt3, 1u);
              if (s3 < 256u) buf3[s3] = ((u64)kf << 32) | (u32)(~(u32)p);
              atomicAdd(&histm[sub4 + ((kf >> 8) & 255u)], 1u);
            }
          }
        }
      }
    }
    select256s(K);
    const u32 b3 = s_sel; K = s_rem;
    const bool buffered = (s_cnt3 <= 256u);  // uniform (shared, post-barrier)

    // ---- pass 4: low byte of full key ----
    for (int j = tid; j < 4 * 257; j += 256) histm[j] = 0u;
    __syncthreads();
    if (buffered) {
      u32 n3 = s_cnt3;
      for (u32 i = tid; i < n3; i += 256) {
        u32 kf = (u32)(buf3[i] >> 32);
        if (((kf >> 8) & 255u) == b3) atomicAdd(&histm[sub4 + (kf & 255u)], 1u);
      }
    } else {  // rare exact fallback: rescan
      for (int i = tid; i < NP2PAD; i += 256) {
        u32 v = krow32[i];
#pragma unroll
        for (int h = 0; h < 2; ++h) {
          u32 k16 = (h == 0) ? (v & 0xFFFFu) : (v >> 16);
          if (k16 == pfx16) {
            u32 kf = fkey(loadscore(2 * i + h));
            if (((kf >> 8) & 255u) == b3) atomicAdd(&histm[sub4 + (kf & 255u)], 1u);
          }
        }
      }
    }
    select256s(K);
    T = (pfx16 << 16) | (b3 << 8) | s_sel; K = s_rem;
    G = TOPK - K;

    // ---- finalize boundary bin: strict-greater + ties ----
    if (buffered) {
      u32 n3 = s_cnt3;
      for (u32 i = tid; i < n3; i += 256) {
        u64 e = buf3[i];
        u32 kf = (u32)(e >> 32);
        if (kf > T) {
          keys[atomicAdd(&s_cnt, 1u)] = e;
        } else if (kf == T) {
          u32 t2 = atomicAdd(&s_cnt2, 1u);
          u32 sl = G + t2;
          if (sl < 256u) keys[sl] = e;
        }
      }
    } else {  // rare exact fallback
      for (int i = tid; i < NP2PAD; i += 256) {
        u32 v = krow32[i];
#pragma unroll
        for (int h = 0; h < 2; ++h) {
          u32 k16 = (h == 0) ? (v & 0xFFFFu) : (v >> 16);
          if (k16 == pfx16) {
            int p = 2 * i + h;
            u32 kf = fkey(loadscore(p));
            if (kf > T) {
              keys[atomicAdd(&s_cnt, 1u)] = ((u64)kf << 32) | (u32)(~(u32)p);
            } else if (kf == T) {
              u32 t2 = atomicAdd(&s_cnt2, 1u);
              u32 sl = G + t2;
              if (sl < 256u) keys[sl] = ((u64)kf << 32) | (u32)(~(u32)p);
            }
          }
        }
      }
    }
    __syncthreads();
  } else {
    T = NEGKEY;
    G = TOPK - K;  // scan-B keys writes complete (select barrier)
    for (int k = (int)G + tid; k < TOPK; k += 256)
      keys[k] = ((u64)T << 32) | 0xFFFFFFFFull;  // inert filler
    __syncthreads();
  }

  // ---- bitonic sort 256 u64 descending (score desc, prior asc via ~p) ----
  for (u32 kk = 2; kk <= 256; kk <<= 1) {
    for (u32 j = kk >> 1; j > 0; j >>= 1) {
      u32 ixj = (u32)tid ^ j;
      if (ixj > (u32)tid) {
        u64 a = keys[tid], bb = keys[ixj];
        bool asc = (tid & kk) != 0;
        if (asc ? (a > bb) : (a < bb)) { keys[tid] = bb; keys[ixj] = a; }
      }
      __syncthreads();
    }
  }

  // ---- decode 200 candidates; write boxes to global + LDS ----
  if (tid < TOPK) {
    u64 e = keys[tid];
    float myscore = unfkey((u32)(e >> 32));
    int p = (int)(~(u32)e);
    const float* lp = loc + ((size_t)b * NP + p) * 4;
    const float* pp = prior + (size_t)p * 4;
    const float* vp = prior + (size_t)NP * 4 + (size_t)p * 4;
    float p0 = pp[0], p1 = pp[1], p2 = pp[2], p3 = pp[3];
    float pw = p2 - p0, ph = p3 - p1;
    float pcx = (p0 + p2) * 0.5f, pcy = (p1 + p3) * 0.5f;
    float cx = vp[0] * lp[0] * pw + pcx;
    float cy = vp[1] * lp[1] * ph + pcy;
    float w = expf(vp[2] * lp[2]) * pw;
    float h = expf(vp[3] * lp[3]) * ph;
    float rx0 = cx - w * 0.5f, ry0 = cy - h * 0.5f;
    float rx1 = cx + w * 0.5f, ry1 = cy + h * 0.5f;
    float rarea = fmaxf(rx1 - rx0, 0.f) * fmaxf(ry1 - ry0, 0.f);
    bx0[tid] = rx0; bx1[tid] = ry0; bx2[tid] = rx1; bx3[tid] = ry1;
    barea[tid] = rarea; bscore[tid] = myscore;
    float* bp = cbox + (keptBase + tid) * 4;
    bp[0] = rx0; bp[1] = ry0; bp[2] = rx1; bp[3] = ry1;
  }
  __syncthreads();

  // ---- greedy NMS: single wave, zero barriers (4 candidates per lane) ----
  if (tid < 64) {
    const int lane = tid;
    float sx0[4], sy0[4], sx1[4], sy1[4], sar[4], ssc[4];
    int sup[4] = {0, 0, 0, 0};
    int keepm = 0;
#pragma unroll
    for (int s = 0; s < 4; ++s) {
      int cc2 = s * 64 + lane;
      if (cc2 < TOPK) {
        sx0[s] = bx0[cc2]; sy0[s] = bx1[cc2]; sx1[s] = bx2[cc2]; sy1[s] = bx3[cc2];
        sar[s] = barea[cc2]; ssc[s] = bscore[cc2];
      } else {
        sx0[s] = 0.f; sy0[s] = 0.f; sx1[s] = 0.f; sy1[s] = 0.f;
        sar[s] = 0.f; ssc[s] = -1.f;  // never kept
      }
    }
#pragma unroll
    for (int s = 0; s < 4; ++s) {
      for (int j = 0; j < 64; ++j) {  // candidate i = s*64+j, in order
        float sc_i = __shfl(ssc[s], j);
        int sup_i = __shfl(sup[s], j);
        if (sc_i > CONF_THR && sup_i == 0) {  // wave-uniform branch
          if (j == lane) keepm |= 1 << s;
          float a0 = __shfl(sx0[s], j), a1 = __shfl(sy0[s], j);
          float a2 = __shfl(sx1[s], j), a3 = __shfl(sy1[s], j);
          float aa = __shfl(sar[s], j);
#pragma unroll
          for (int s2 = 0; s2 < 4; ++s2) {
            float xx1 = fmaxf(a0, sx0[s2]), yy1 = fmaxf(a1, sy0[s2]);
            float xx2 = fminf(a2, sx1[s2]), yy2 = fminf(a3, sy1[s2]);
            float inter = fmaxf(xx2 - xx1, 0.f) * fmaxf(yy2 - yy1, 0.f);
            float uni = aa + sar[s2] - inter;
            float iou = inter / fmaxf(uni, 1e-10f);
            if (iou > NMS_THR) sup[s2] = 1;
          }
        }
      }
    }
#pragma unroll
    for (int s = 0; s < 4; ++s) {
      int cc2 = s * 64 + lane;
      if (cc2 < TOPK)
        kept[keptBase + cc2] = ((keepm >> s) & 1) ? ssc[s] : 0.f;
    }
  }
}

// ---------------------------------------------------------------------------
// Kernel 1 (fallback, proven): strided scan version for small ws_size
// ---------------------------------------------------------------------------
__global__ __launch_bounds__(256) void perclass_fallback(
    const float* __restrict__ loc, const float* __restrict__ conf,
    const float* __restrict__ prior, float* __restrict__ kept,
    float* __restrict__ cbox) {
  __shared__ u16 skey[NP];
  __shared__ unsigned int hist[256];
  __shared__ u64 keys[256];
  __shared__ float bx0[TOPK], bx1[TOPK], bx2[TOPK], bx3[TOPK];
  __shared__ float barea[TOPK], bscore[TOPK];
  __shared__ unsigned char sup[TOPK], keepf[TOPK];
  __shared__ unsigned int s_sel, s_rem, s_cnt, s_cnt2;

  const int tid = threadIdx.x;
  const int nwg = NB * NCLS;
  int i0 = blockIdx.x;
  int bc = (i0 & 7) * (nwg / 8) + (i0 >> 3);
  const int b = bc / NCLS, c = bc % NCLS;
  const size_t keptBase = (size_t)bc * TOPK;

  if (c == 0) {
    for (int k = tid; k < TOPK; k += 256) {
      kept[keptBase + k] = 0.f;
      float* bp = cbox + (keptBase + k) * 4;
      bp[0] = 0.f; bp[1] = 0.f; bp[2] = 0.f; bp[3] = 0.f;
    }
    return;
  }

  const float* confb = conf + (size_t)b * NP * NCLS + c;
  auto loadscore = [&](int p) -> float {
    float s = confb[(size_t)p * NCLS];
    return (s > CONF_THR) ? s : -1.0f;
  };

  for (int p = tid; p < NP; p += 256)
    skey[p] = (u16)(fkey(loadscore(p)) >> 16);
  __syncthreads();

  auto select_bin = [&](u32 Kin) {
    if (tid == 0) {
      u32 rem = Kin;
      int bin = 255;
      for (; bin > 0; --bin) {
        u32 cnt = hist[bin];
        if (cnt >= rem) break;
        rem -= cnt;
      }
      s_sel = (u32)bin; s_rem = rem;
    }
    __syncthreads();
  };

  u32 K = TOPK;
  hist[tid] = 0; __syncthreads();
  for (int p = tid; p < NP; p += 256) atomicAdd(&hist[skey[p] >> 8], 1u);
  __syncthreads();
  select_bin(K);
  u32 pfx16 = s_sel << 8; K = s_rem;

  hist[tid] = 0; __syncthreads();
  {
    u32 hb = pfx16 >> 8;
    for (int p = tid; p < NP; p += 256) {
      u16 v = skey[p];
      if ((u32)(v >> 8) == hb) atomicAdd(&hist[v & 255], 1u);
    }
  }
  __syncthreads();
  select_bin(K);
  pfx16 |= s_sel; K = s_rem;

  const bool fillMode = (pfx16 == NEGK16);
  u32 T;
  if (!fillMode) {
    u32 pfull = pfx16 << 16;
    hist[tid] = 0; __syncthreads();
    for (int p = tid; p < NP; p += 256) {
      if ((u32)skey[p] == pfx16) {
        u32 kf = fkey(loadscore(p));
        atomicAdd(&hist[(kf >> 8) & 255], 1u);
      }
    }
    __syncthreads();
    select_bin(K);
    pfull |= s_sel << 8; K = s_rem;

    hist[tid] = 0; __syncthreads();
    for (int p = tid; p < NP; p += 256) {
      if ((u32)skey[p] == pfx16) {
        u32 kf = fkey(loadscore(p));
        if ((kf >> 8) == (pfull >> 8)) atomicAdd(&hist[kf & 255], 1u);
      }
    }
    __syncthreads();
    select_bin(K);
    T = pfull | s_sel; K = s_rem;
  } else {
    T = NEGKEY;
  }

  const u32 G = TOPK - K;
  keys[tid] = 0;
  if (tid == 0) { s_cnt = 0; s_cnt2 = 0; }
  __syncthreads();
  for (int p = tid; p < NP; p += 256) {
    u32 v = skey[p];
    if (v > pfx16) {
      float s = loadscore(p);
      u32 slot = atomicAdd(&s_cnt, 1u);
      keys[slot] = ((u64)fkey(s) << 32) | (u32)(~(u32)p);
    } else if (!fillMode && v == pfx16) {
      float s = loadscore(p);
      u32 kf = fkey(s);
      if (kf > T) {
        u32 slot = atomicAdd(&s_cnt, 1u);
        keys[slot] = ((u64)kf << 32) | (u32)(~(u32)p);
      } else if (kf == T) {
        u32 t2 = atomicAdd(&s_cnt2, 1u);
        u32 slot = G + t2;
        if (slot < 256u) keys[slot] = ((u64)kf << 32) | (u32)(~(u32)p);
      }
    }
  }
  __syncthreads();
  if (fillMode) {
    for (int k = (int)G + tid; k < TOPK; k += 256)
      keys[k] = ((u64)T << 32) | 0xFFFFFFFFull;
  }
  __syncthreads();

  for (u32 kk = 2; kk <= 256; kk <<= 1) {
    for (u32 j = kk >> 1; j > 0; j >>= 1) {
      u32 ixj = (u32)tid ^ j;
      if (ixj > (u32)tid) {
        u64 a = keys[tid], bb = keys[ixj];
        bool asc = (tid & kk) != 0;
        if (asc ? (a > bb) : (a < bb)) { keys[tid] = bb; keys[ixj] = a; }
      }
      __syncthreads();
    }
  }

  if (tid < TOPK) {
    u64 e = keys[tid];
    float s = unfkey((u32)(e >> 32));
    int p = (int)(~(u32)e);
    const float* lp = loc + ((size_t)b * NP + p) * 4;
    const float* pp = prior + (size_t)p * 4;
    const float* vp = prior + (size_t)NP * 4 + (size_t)p * 4;
    float p0 = pp[0], p1 = pp[1], p2 = pp[2], p3 = pp[3];
    float pw = p2 - p0, ph = p3 - p1;
    float pcx = (p0 + p2) * 0.5f, pcy = (p1 + p3) * 0.5f;
    float cx = vp[0] * lp[0] * pw + pcx;
    float cy = vp[1] * lp[1] * ph + pcy;
    float w = expf(vp[2] * lp[2]) * pw;
    float h = expf(vp[3] * lp[3]) * ph;
    float x0 = cx - w * 0.5f, y0 = cy - h * 0.5f;
    float x1 = cx + w * 0.5f, y1 = cy + h * 0.5f;
    bx0[tid] = x0; bx1[tid] = y0; bx2[tid] = x1; bx3[tid] = y1;
    barea[tid] = fmaxf(x1 - x0, 0.f) * fmaxf(y1 - y0, 0.f);
    bscore[tid] = s;
    sup[tid] = 0;
    keepf[tid] = 0;
  }
  __syncthreads();

  for (int i = 0; i < TOPK; ++i) {
    bool kept_i = (bscore[i] > CONF_THR) && (sup[i] == 0);
    __syncthreads();
    if (kept_i) {
      if (tid < TOPK) {
        float xx1 = fmaxf(bx0[i], bx0[tid]);
        float yy1 = fmaxf(bx1[i], bx1[tid]);
        float xx2 = fminf(bx2[i], bx2[tid]);
        float yy2 = fminf(bx3[i], bx3[tid]);
        float inter = fmaxf(xx2 - xx1, 0.f) * fmaxf(yy2 - yy1, 0.f);
        float uni = barea[i] + barea[tid] - inter;
        float iou = inter / fmaxf(uni, 1e-10f);
        if (iou > NMS_THR) sup[tid] = 1;
      }
      if (tid == 0) keepf[i] = 1;
    }
    __syncthreads();
  }

  if (tid < TOPK) {
    kept[keptBase + tid] = keepf[tid] ? bscore[tid] : 0.f;
    float* bp = cbox + (keptBase + tid) * 4;
    bp[0] = bx0[tid]; bp[1] = bx1[tid]; bp[2] = bx2[tid]; bp[3] = bx3[tid];
  }
}

// ---------------------------------------------------------------------------
// Kernel 2 (v2): per-batch top-200 with parallel select + skewed hist
// ---------------------------------------------------------------------------
__global__ __launch_bounds__(256) void final_topk(
    const float* __restrict__ kept, const float* __restrict__ cbox,
    float* __restrict__ out) {
  __shared__ u32 histm[4 * 257];
  __shared__ u32 ssuf[256];
  __shared__ u64 keys[256];
  __shared__ u32 s_sel, s_rem, s_cnt, s_cnt2;

  const int tid = threadIdx.x;
  const int b = blockIdx.x;
  const float* sc = kept + (size_t)b * NFLAT;
  const int sub4 = (tid & 3) * 257;

  auto select256s = [&](u32 Kin) {
    __syncthreads();
    u32 cntv = histm[tid] + histm[257 + tid] + histm[514 + tid] + histm[771 + tid];
    ssuf[tid] = cntv;
    __syncthreads();
    for (int d = 1; d < 256; d <<= 1) {
      u32 add = (tid + d < 256) ? ssuf[tid + d] : 0u;
      __syncthreads();
      ssuf[tid] += add;
      __syncthreads();
    }
    u32 s = ssuf[tid], above = s - cntv;
    if (s >= Kin && above < Kin) { s_sel = (u32)tid; s_rem = Kin - above; }
    __syncthreads();
  };

  u32 pfx = 0;
  u32 K = KEEPK;
  for (int shift = 24; shift >= 0; shift -= 8) {
    for (int j = tid; j < 4 * 257; j += 256) histm[j] = 0u;
    __syncthreads();
    u32 himask = (shift == 24) ? 0u : (0xFFFFFFFFu << (shift + 8));
    for (int p = tid; p < NFLAT; p += 256) {
      u32 kf = fkey(sc[p]);
      if ((kf & himask) == pfx) atomicAdd(&histm[sub4 + ((kf >> shift) & 255u)], 1u);
    }
    select256s(K);
    pfx |= s_sel << shift; K = s_rem;
  }

  const bool fill2 = (pfx == fkey(0.0f));
  const u32 G = KEEPK - K;
  keys[tid] = 0;
  if (tid == 0) { s_cnt = 0; s_cnt2 = 0; }
  __syncthreads();
  for (int p = tid; p < NFLAT; p += 256) {
    u32 kf = fkey(sc[p]);
    if (kf > pfx) {
      u32 slot = atomicAdd(&s_cnt, 1u);
      keys[slot] = ((u64)kf << 32) | (u32)(~(u32)p);
    } else if (!fill2 && kf == pfx) {
      u32 t2 = atomicAdd(&s_cnt2, 1u);
      u32 slot = G + t2;
      if (slot < 256u) keys[slot] = ((u64)kf << 32) | (u32)(~(u32)p);
    }
  }
  __syncthreads();
  if (fill2) {
    for (int k = (int)G + tid; k < KEEPK; k += 256)
      keys[k] = ((u64)pfx << 32) | 0xFFFFFFFFull;
  }
  __syncthreads();

  for (u32 kk = 2; kk <= 256; kk <<= 1) {
    for (u32 j = kk >> 1; j > 0; j >>= 1) {
      u32 ixj = (u32)tid ^ j;
      if (ixj > (u32)tid) {
        u64 a = keys[tid], bb = keys[ixj];
        bool asc = (tid & kk) != 0;
        if (asc ? (a > bb) : (a < bb)) { keys[tid] = bb; keys[ixj] = a; }
      }
      __syncthreads();
    }
  }

  if (tid < KEEPK) {
    u64 e = keys[tid];
    float s = unfkey((u32)(e >> 32));
    u32 fi = ~(u32)e;
    float r0 = 0.f, r1 = 0.f, r2 = 0.f, r3 = 0.f, r4 = 0.f, r5 = 0.f, r6 = 0.f;
    if (s > 0.f) {
      r0 = (float)b;
      r1 = (float)(fi / TOPK);
      r2 = s;
      const float* bp = cbox + ((size_t)b * NFLAT + fi) * 4;
      r3 = bp[0]; r4 = bp[1]; r5 = bp[2]; r6 = bp[3];
    }
    float* op = out + ((size_t)b * KEEPK + tid) * 7;
    op[0] = r0; op[1] = r1; op[2] = r2; op[3] = r3;
    op[4] = r4; op[5] = r5; op[6] = r6;
  }
}

extern "C" void kernel_launch(void* const* d_in, const int* in_sizes, int n_in,
                              void* d_out, int out_size, void* d_ws, size_t ws_size,
                              hipStream_t stream) {
  const float* loc = (const float*)d_in[0];
  const float* conf = (const float*)d_in[1];
  const float* prior = (const float*)d_in[2];
  float* out = (float*)d_out;

  float* kept = (float*)d_ws;                     // NB*NCLS*TOPK floats
  float* cbox = kept + (size_t)NB * NCLS * TOPK;  // NB*NCLS*TOPK*4 floats
  const size_t baseBytes = (size_t)NB * NCLS * TOPK * 5 * sizeof(float);   // 10.37 MB
  const size_t keysBytes = (size_t)NB * NCLS * NPPAD * sizeof(u16);        // 127.4 MB

  if (ws_size >= baseBytes + keysBytes) {
    u16* keys16 = (u16*)((char*)d_ws + baseBytes);
    build_keys<<<dim3(NB * NCHUNK), dim3(256), 0, stream>>>(conf, keys16);
    perclass_v6<<<dim3(NB * NCLS), dim3(256), 0, stream>>>(loc, conf, prior,
                                                           keys16, kept, cbox);
  } else {
    perclass_fallback<<<dim3(NB * NCLS), dim3(256), 0, stream>>>(loc, conf,
                                                                 prior, kept, cbox);
  }
  final_topk<<<dim3(NB), dim3(256), 0, stream>>>(kept, cbox, out);
}